// Round 5
// baseline (899.086 us; speedup 1.0000x reference)
//
#include <hip/hip_runtime.h>
#include <hip/hip_bf16.h>

// CHNN=1024, K=L=2048. Inputs fp32, OUTPUT fp32 (rounds 3-4 wrote bf16 into an
// fp32-read buffer -> deterministic 0.72 absmax: scrambled first half + zero
// second half). Intermediates fp32 in 32 MB liveness-compacted workspace
// (layout proven non-corrupting: identical results at 20 MB and 32 MB).

__device__ __forceinline__ float ldf(const float* p) { return *p; }

// C(M,N) = op(A) @ B [+ bias] [relu].  op(A)=A (M x K, row-major) or A^T with A stored (K x M).
// B is (K x N) row-major.  BIAS_MODE: 0 none, 1 per-row bias[m], 2 per-col bias[n].
// Tile 64x64x16, block 16x16, 4x4 accumulators per thread.
template<bool TRANS_A, int BIAS_MODE, bool RELU>
__global__ __launch_bounds__(256)
void gemm64(const float* __restrict__ A, const float* __restrict__ B,
            const float* __restrict__ bias,
            float* __restrict__ C, int M, int N, int K)
{
    __shared__ float As[16][68];   // 272B row stride: 16B multiple, float4-aligned
    __shared__ float Bs[16][68];
    const int tx = threadIdx.x, ty = threadIdx.y;
    const int tid = ty * 16 + tx;
    const int m0 = blockIdx.y * 64, n0 = blockIdx.x * 64;
    float acc[4][4] = {};

    for (int k0 = 0; k0 < K; k0 += 16) {
        if (TRANS_A) {
            #pragma unroll
            for (int r = 0; r < 4; ++r) {
                int idx = r * 256 + tid;
                int kk = idx >> 6, mm = idx & 63;
                As[kk][mm] = ldf(A + (size_t)(k0 + kk) * M + (m0 + mm));
            }
        } else {
            #pragma unroll
            for (int r = 0; r < 4; ++r) {
                int idx = r * 256 + tid;
                int mm = idx >> 4, kk = idx & 15;
                As[kk][mm] = ldf(A + (size_t)(m0 + mm) * K + (k0 + kk));
            }
        }
        #pragma unroll
        for (int r = 0; r < 4; ++r) {
            int idx = r * 256 + tid;
            int kk = idx >> 6, nn = idx & 63;
            Bs[kk][nn] = ldf(B + (size_t)(k0 + kk) * N + (n0 + nn));
        }
        __syncthreads();
        #pragma unroll
        for (int kk = 0; kk < 16; ++kk) {
            float4 av = *reinterpret_cast<const float4*>(&As[kk][ty * 4]);
            float4 bv = *reinterpret_cast<const float4*>(&Bs[kk][tx * 4]);
            float a[4] = {av.x, av.y, av.z, av.w};
            float b[4] = {bv.x, bv.y, bv.z, bv.w};
            #pragma unroll
            for (int i = 0; i < 4; ++i)
                #pragma unroll
                for (int j = 0; j < 4; ++j)
                    acc[i][j] += a[i] * b[j];
        }
        __syncthreads();
    }
    #pragma unroll
    for (int i = 0; i < 4; ++i) {
        #pragma unroll
        for (int j = 0; j < 4; ++j) {
            float v = acc[i][j];
            if (BIAS_MODE == 1) v += bias[m0 + ty * 4 + i];
            if (BIAS_MODE == 2) v += bias[n0 + tx * 4 + j];
            if (RELU) v = fmaxf(v, 0.0f);
            C[(size_t)(m0 + ty * 4 + i) * N + (n0 + tx * 4 + j)] = v;
        }
    }
}

// In-place softmax over axis 0 (rows) of S (R x C). Block (64,16); coalesced.
__global__ __launch_bounds__(1024)
void col_softmax(float* __restrict__ S, int R, int C)
{
    __shared__ float red[16][64];
    __shared__ float bc[64];
    const int tx = threadIdx.x, ty = threadIdx.y;
    const int col = blockIdx.x * 64 + tx;
    float m = -1e30f;
    for (int r = ty; r < R; r += 16) m = fmaxf(m, S[(size_t)r * C + col]);
    red[ty][tx] = m;
    __syncthreads();
    if (ty == 0) {
        for (int t = 1; t < 16; ++t) m = fmaxf(m, red[t][tx]);
        bc[tx] = m;
    }
    __syncthreads();
    m = bc[tx];
    float s = 0.0f;
    for (int r = ty; r < R; r += 16) {
        size_t idx = (size_t)r * C + col;
        float e = expf(S[idx] - m);
        S[idx] = e;
        s += e;
    }
    red[ty][tx] = s;
    __syncthreads();
    if (ty == 0) {
        for (int t = 1; t < 16; ++t) s += red[t][tx];
        bc[tx] = 1.0f / s;
    }
    __syncthreads();
    float inv = bc[tx];
    for (int r = ty; r < R; r += 16) S[(size_t)r * C + col] *= inv;
}

// In-place softmax over the last axis, one block per row.
__global__ __launch_bounds__(256)
void row_softmax(float* __restrict__ A, int N)
{
    __shared__ float red[256];
    const int t = threadIdx.x;
    float* p = A + (size_t)blockIdx.x * N;
    float m = -1e30f;
    for (int i = t; i < N; i += 256) m = fmaxf(m, p[i]);
    red[t] = m;
    __syncthreads();
    for (int s = 128; s > 0; s >>= 1) {
        if (t < s) red[t] = fmaxf(red[t], red[t + s]);
        __syncthreads();
    }
    m = red[0];
    __syncthreads();
    float sum = 0.0f;
    for (int i = t; i < N; i += 256) {
        float e = expf(p[i] - m);
        p[i] = e;
        sum += e;
    }
    red[t] = sum;
    __syncthreads();
    for (int s = 128; s > 0; s >>= 1) {
        if (t < s) red[t] += red[t + s];
        __syncthreads();
    }
    float inv = 1.0f / red[0];
    for (int i = t; i < N; i += 256) p[i] *= inv;
}

// out (C x R) fp32 = transpose of in (R x C) fp32. Block (32,8), 32x32 LDS tile.
__global__ __launch_bounds__(256)
void transpose_f32(const float* __restrict__ in, float* __restrict__ out, int R, int C)
{
    __shared__ float tile[32][33];
    const int bx = blockIdx.x * 32;   // column base in `in` (C dim)
    const int by = blockIdx.y * 32;   // row base in `in` (R dim)
    const int tx = threadIdx.x, ty = threadIdx.y;
    #pragma unroll
    for (int i = ty; i < 32; i += 8)
        tile[i][tx] = in[(size_t)(by + i) * C + (bx + tx)];
    __syncthreads();
    #pragma unroll
    for (int i = ty; i < 32; i += 8)
        out[(size_t)(bx + i) * R + (by + tx)] = tile[tx][i];
}

extern "C" void kernel_launch(void* const* d_in, const int* in_sizes, int n_in,
                              void* d_out, int out_size, void* d_ws, size_t ws_size,
                              hipStream_t stream)
{
    const float* vc    = (const float*)d_in[0];
    const float* vm    = (const float*)d_in[1];
    const float* W_ak  = (const float*)d_in[2];
    const float* b_ak  = (const float*)d_in[3];
    const float* W_c   = (const float*)d_in[4];
    const float* b_c   = (const float*)d_in[5];
    const float* W_mad = (const float*)d_in[6];
    const float* b_mad = (const float*)d_in[7];
    const float* W_gcn = (const float*)d_in[8];
    const float* b_gcn = (const float*)d_in[9];
    float* out = (float*)d_out;

    // Workspace layout: 8M floats = 32 MB total, liveness-compacted.
    //   [0,2M):  vmr   (w:3, r:4,7)   then out0 (w:9, r:10)
    //   [2M,6M): S     (w:1, r:2,4)
    //   [2M,4M):                       then vma (w:5, r:6), then x (w:7, r:9)
    //   [6M,8M): vma1  (w:4, r:5)
    //   [4M,8M):                       then Amat (w:6, r:8,9)
    float* ws = (float*)d_ws;
    const size_t M1 = 1u << 20;       // 1M floats
    float* vmr  = ws;                 // [0, 2M)
    float* S    = ws + 2 * M1;        // [2M, 6M)
    float* vma1 = ws + 6 * M1;        // [6M, 8M)
    float* vma  = ws + 2 * M1;        // [2M, 4M)  (S dead after step 4)
    float* Amat = ws + 4 * M1;        // [4M, 8M)  (S half + vma1 dead)
    float* x    = ws + 2 * M1;        // [2M, 4M)  (vma dead after step 6)
    float* out0 = ws;                 // [0, 2M)   (vmr dead after step 7)

    dim3 blk(16, 16);

    // 1. S = W_ak @ vc + b_ak        (2048 x 2048, K=1024)
    gemm64<false, 1, false>
        <<<dim3(32, 32), blk, 0, stream>>>(W_ak, vc, b_ak, S, 2048, 2048, 1024);
    // 2. softmax over the K index (axis 0 of S)
    col_softmax<<<dim3(32), dim3(64, 16), 0, stream>>>(S, 2048, 2048);
    // 3. vmr = relu(W_c @ vm + b_c)  (1024 x 2048, K=1024)
    gemm64<false, 1, true>
        <<<dim3(32, 16), blk, 0, stream>>>(W_c, vm, b_c, vmr, 1024, 2048, 1024);
    // 4. vma1 = vmr @ S_sm           (1024 x 2048, K=2048)
    gemm64<false, 0, false>
        <<<dim3(32, 16), blk, 0, stream>>>(vmr, S, nullptr, vma1, 1024, 2048, 2048);
    // 5. vma = W_mad @ vma1 + b_mad  (1024 x 2048, K=1024)
    gemm64<false, 1, false>
        <<<dim3(32, 16), blk, 0, stream>>>(W_mad, vma1, b_mad, vma, 1024, 2048, 1024);
    // 6. Amat = vma^T @ vma          (2048 x 2048, K=1024)
    gemm64<true, 0, false>
        <<<dim3(32, 32), blk, 0, stream>>>(vma, vma, nullptr, Amat, 2048, 2048, 1024);
    // 7. x = vmr^T @ W_gcn + b_gcn   (2048 x 1024, K=1024), bias per column
    gemm64<true, 2, false>
        <<<dim3(16, 32), blk, 0, stream>>>(vmr, W_gcn, b_gcn, x, 2048, 1024, 1024);
    // 8. row softmax of Amat
    row_softmax<<<dim3(2048), dim3(256), 0, stream>>>(Amat, 2048);
    // 9. out0 = Amat_sm @ x          (2048 x 1024, K=2048)
    gemm64<false, 0, false>
        <<<dim3(16, 32), blk, 0, stream>>>(Amat, x, nullptr, out0, 2048, 1024, 2048);
    // 10. d_out[c*2048 + l] = out0[l*1024 + c]  (fp32 output!)
    transpose_f32<<<dim3(1024 / 32, 2048 / 32), dim3(32, 8), 0, stream>>>(out0, out, 2048, 1024);
}

// Round 6
// 299.791 us; speedup vs baseline: 2.9990x; 2.9990x over previous
//
#include <hip/hip_runtime.h>
#include <hip/hip_bf16.h>

// CHNN=1024, K=L=2048. Inputs fp32, output fp32. All GEMMs via bf16 MFMA
// (16x16x32), fp32 accumulation. All GEMM operands stored k-contiguous
// ("TN": C[m][n] = sum_k A[m][k]*B[n][k]) so LDS staging is straight copies.
// Workspace 30 MB, liveness-packed (32 MB proven safe in round 5).

typedef __bf16 bf16x8 __attribute__((ext_vector_type(8)));
typedef __bf16 bf16x4 __attribute__((ext_vector_type(4)));
typedef float  f32x4  __attribute__((ext_vector_type(4)));

// ---------------- MFMA TN GEMM ----------------
// C(M,N) = A(M,K) * B(N,K)^T, A/B bf16 k-contiguous, C = OUT_T.
// BIAS_MODE: 0 none, 1 bias[m], 2 bias[n]. Block 256 = 4 waves; tile 128x128,
// BK=32; each wave computes a 64x64 quadrant as 4x4 MFMA tiles.
template<typename OUT_T, int BIAS_MODE, bool RELU>
__global__ __launch_bounds__(256)
void gemm_tn(const __bf16* __restrict__ A, const __bf16* __restrict__ B,
             const float* __restrict__ bias, OUT_T* __restrict__ C,
             int M, int N, int K)
{
    __shared__ __bf16 sA[128 * 32];
    __shared__ __bf16 sB[128 * 32];
    const int tid  = threadIdx.x;
    const int lane = tid & 63;
    const int m0 = blockIdx.y * 128, n0 = blockIdx.x * 128;
    const int wv = tid >> 6;
    const int mw = (wv >> 1) * 64, nw = (wv & 1) * 64;

    f32x4 acc[4][4];
    #pragma unroll
    for (int i = 0; i < 4; ++i)
        #pragma unroll
        for (int j = 0; j < 4; ++j)
            acc[i][j] = (f32x4){0.f, 0.f, 0.f, 0.f};

    // Staging: thread t copies 32 B of each tile: row t>>1, bf16 cols (t&1)*16..+15.
    const int srow = tid >> 1;
    const int sk   = (tid & 1) * 16;
    const __bf16* gA = A + (size_t)(m0 + srow) * K + sk;
    const __bf16* gB = B + (size_t)(n0 + srow) * K + sk;
    __bf16* lA = &sA[srow * 32 + sk];
    __bf16* lB = &sB[srow * 32 + sk];

    uint4 ra0 = *(const uint4*)(gA);
    uint4 ra1 = *(const uint4*)(gA + 8);
    uint4 rb0 = *(const uint4*)(gB);
    uint4 rb1 = *(const uint4*)(gB + 8);

    for (int k0 = 0; k0 < K; k0 += 32) {
        __syncthreads();               // prev iteration finished reading LDS
        *(uint4*)(lA)     = ra0;
        *(uint4*)(lA + 8) = ra1;
        *(uint4*)(lB)     = rb0;
        *(uint4*)(lB + 8) = rb1;
        __syncthreads();
        if (k0 + 32 < K) {             // prefetch next tile into registers
            ra0 = *(const uint4*)(gA + k0 + 32);
            ra1 = *(const uint4*)(gA + k0 + 40);
            rb0 = *(const uint4*)(gB + k0 + 32);
            rb1 = *(const uint4*)(gB + k0 + 40);
        }
        bf16x8 af[4], bfr[4];
        #pragma unroll
        for (int i = 0; i < 4; ++i) {
            af[i]  = *(const bf16x8*)&sA[(mw + i * 16 + (lane & 15)) * 32 + (lane >> 4) * 8];
            bfr[i] = *(const bf16x8*)&sB[(nw + i * 16 + (lane & 15)) * 32 + (lane >> 4) * 8];
        }
        #pragma unroll
        for (int i = 0; i < 4; ++i)
            #pragma unroll
            for (int j = 0; j < 4; ++j)
                acc[i][j] = __builtin_amdgcn_mfma_f32_16x16x32_bf16(af[i], bfr[j], acc[i][j], 0, 0, 0);
    }

    // Epilogue: C/D layout col=lane&15, row=(lane>>4)*4+reg (m89/m91-verified).
    #pragma unroll
    for (int i = 0; i < 4; ++i) {
        #pragma unroll
        for (int j = 0; j < 4; ++j) {
            const int col = n0 + nw + j * 16 + (lane & 15);
            #pragma unroll
            for (int r = 0; r < 4; ++r) {
                const int row = m0 + mw + i * 16 + (lane >> 4) * 4 + r;
                float v = acc[i][j][r];
                if (BIAS_MODE == 1) v += bias[row];
                if (BIAS_MODE == 2) v += bias[col];
                if (RELU) v = fmaxf(v, 0.f);
                C[(size_t)row * N + col] = (OUT_T)v;
            }
        }
    }
}

// ---------------- helpers ----------------
// fp32 -> bf16 cast, 4 elements/thread. n % 1024 == 0.
__global__ __launch_bounds__(256)
void cast_bf16(const float* __restrict__ in, __bf16* __restrict__ out, int n)
{
    int i = (blockIdx.x * 256 + threadIdx.x) * 4;
    float4 v = *(const float4*)&in[i];
    bf16x4 w = { (__bf16)v.x, (__bf16)v.y, (__bf16)v.z, (__bf16)v.w };
    *(bf16x4*)&out[i] = w;
}

// out (C x R) bf16 = transpose of in (R x C) fp32. Block (32,8).
__global__ __launch_bounds__(256)
void transpose_cast_bf16(const float* __restrict__ in, __bf16* __restrict__ out, int R, int C)
{
    __shared__ float t[32][33];
    const int bx = blockIdx.x * 32, by = blockIdx.y * 32;
    const int tx = threadIdx.x, ty = threadIdx.y;
    #pragma unroll
    for (int i = ty; i < 32; i += 8)
        t[i][tx] = in[(size_t)(by + i) * C + (bx + tx)];
    __syncthreads();
    #pragma unroll
    for (int i = ty; i < 32; i += 8)
        out[(size_t)(bx + i) * R + (by + tx)] = (__bf16)t[tx][i];
}

// out (C x R) bf16 = transpose of in (R x C) bf16. Block (32,8).
__global__ __launch_bounds__(256)
void transpose_b16(const __bf16* __restrict__ in, __bf16* __restrict__ out, int R, int C)
{
    __shared__ __bf16 t[32][33];
    const int bx = blockIdx.x * 32, by = blockIdx.y * 32;
    const int tx = threadIdx.x, ty = threadIdx.y;
    #pragma unroll
    for (int i = ty; i < 32; i += 8)
        t[i][tx] = in[(size_t)(by + i) * C + (bx + tx)];
    __syncthreads();
    #pragma unroll
    for (int i = ty; i < 32; i += 8)
        out[(size_t)(bx + i) * R + (by + tx)] = t[tx][i];
}

// out (C x R) fp32 = transpose of in (R x C) fp32. Block (32,8).
__global__ __launch_bounds__(256)
void transpose_f32(const float* __restrict__ in, float* __restrict__ out, int R, int C)
{
    __shared__ float t[32][33];
    const int bx = blockIdx.x * 32, by = blockIdx.y * 32;
    const int tx = threadIdx.x, ty = threadIdx.y;
    #pragma unroll
    for (int i = ty; i < 32; i += 8)
        t[i][tx] = in[(size_t)(by + i) * C + (bx + tx)];
    __syncthreads();
    #pragma unroll
    for (int i = ty; i < 32; i += 8)
        out[(size_t)(bx + i) * R + (by + tx)] = t[tx][i];
}

// In-place row softmax over N=2048 bf16; one block per row, 8 elems/thread.
__global__ __launch_bounds__(256)
void row_softmax_bf16(__bf16* __restrict__ A)
{
    __shared__ float red[256];
    const int t = threadIdx.x;
    __bf16* p = A + (size_t)blockIdx.x * 2048;
    bf16x8 v = *(bf16x8*)&p[t * 8];
    float f[8];
    float m = -1e30f;
    #pragma unroll
    for (int r = 0; r < 8; ++r) { f[r] = (float)v[r]; m = fmaxf(m, f[r]); }
    red[t] = m;
    __syncthreads();
    for (int s = 128; s > 0; s >>= 1) {
        if (t < s) red[t] = fmaxf(red[t], red[t + s]);
        __syncthreads();
    }
    m = red[0];
    __syncthreads();
    float sum = 0.f;
    #pragma unroll
    for (int r = 0; r < 8; ++r) { f[r] = expf(f[r] - m); sum += f[r]; }
    red[t] = sum;
    __syncthreads();
    for (int s = 128; s > 0; s >>= 1) {
        if (t < s) red[t] += red[t + s];
        __syncthreads();
    }
    const float inv = 1.f / red[0];
    bf16x8 w;
    #pragma unroll
    for (int r = 0; r < 8; ++r) w[r] = (__bf16)(f[r] * inv);
    *(bf16x8*)&p[t * 8] = w;
}

extern "C" void kernel_launch(void* const* d_in, const int* in_sizes, int n_in,
                              void* d_out, int out_size, void* d_ws, size_t ws_size,
                              hipStream_t stream)
{
    const float* vc    = (const float*)d_in[0];
    const float* vm    = (const float*)d_in[1];
    const float* W_ak  = (const float*)d_in[2];
    const float* b_ak  = (const float*)d_in[3];
    const float* W_c   = (const float*)d_in[4];
    const float* b_c   = (const float*)d_in[5];
    const float* W_mad = (const float*)d_in[6];
    const float* b_mad = (const float*)d_in[7];
    const float* W_gcn = (const float*)d_in[8];
    const float* b_gcn = (const float*)d_in[9];
    float* out = (float*)d_out;

    // Arena (byte offsets, MB units). 30 MB total; all regions reused by liveness:
    //  [0,8):   ST bf16 2048x2048 (w:G1, sm, r:G4)     -> out0 fp32 2048x1024 (w:G9, r:T5)
    //  [8,12):  vcT bf16 2048x1024 (w:T1, r:G1)        -> P low half
    //  [12,16): W_akb bf16 2048x1024 (w:C1, r:G1)      -> P high half  (P w:G6, sm, r:G9)
    //  [16,20): vmT (w:T2,r:G3) -> vma1T (w:G4,r:G5) -> xT (w:G7,r:G9)
    //  [20,22): W_cb (w:C2,r:G3) -> W_madb (w:C3,r:G5) -> W_gcnT (w:T3,r:G7)
    //  [22,26): vmr bf16 1024x2048 (w:G3, r:T4,G4)     -> vmaT bf16 2048x1024 (w:G5, r:G6)
    //  [26,30): vmrT bf16 2048x1024 (w:T4, r:G7)
    char* ws = (char*)d_ws;
    const size_t MB = 1u << 20;
    __bf16* ST     = (__bf16*)(ws);
    float*  out0   = (float*) (ws);
    __bf16* vcT    = (__bf16*)(ws + 8 * MB);
    __bf16* W_akb  = (__bf16*)(ws + 12 * MB);
    __bf16* P      = (__bf16*)(ws + 8 * MB);
    __bf16* vmT    = (__bf16*)(ws + 16 * MB);
    __bf16* vma1T  = (__bf16*)(ws + 16 * MB);
    __bf16* xT     = (__bf16*)(ws + 16 * MB);
    __bf16* W_cb   = (__bf16*)(ws + 20 * MB);
    __bf16* W_madb = (__bf16*)(ws + 20 * MB);
    __bf16* W_gcnT = (__bf16*)(ws + 20 * MB);
    __bf16* vmr    = (__bf16*)(ws + 22 * MB);
    __bf16* vmaT   = (__bf16*)(ws + 22 * MB);
    __bf16* vmrT   = (__bf16*)(ws + 26 * MB);

    const dim3 tb(32, 8);

    // --- prep + pipeline (order respects all region reuse) ---
    // T1: vcT[l][c] <- vc (1024x2048 fp32)
    transpose_cast_bf16<<<dim3(64, 32), tb, 0, stream>>>(vc, vcT, 1024, 2048);
    // C1: W_akb <- W_ak (2048x1024)
    cast_bf16<<<dim3(2048), 256, 0, stream>>>(W_ak, W_akb, 2048 * 1024);
    // G1: ST[l][k] = sum_c vcT[l][c]*W_akb[k][c] + b_ak[k]   (M=2048,N=2048,K=1024)
    gemm_tn<__bf16, 2, false><<<dim3(16, 16), 256, 0, stream>>>(vcT, W_akb, b_ak, ST, 2048, 2048, 1024);
    // SM1: softmax over k (rows of ST)
    row_softmax_bf16<<<dim3(2048), 256, 0, stream>>>(ST);
    // T2: vmT[l][c] <- vm
    transpose_cast_bf16<<<dim3(64, 32), tb, 0, stream>>>(vm, vmT, 1024, 2048);
    // C2: W_cb <- W_c (1024x1024)
    cast_bf16<<<dim3(1024), 256, 0, stream>>>(W_c, W_cb, 1024 * 1024);
    // G3: vmr[c][l] = relu(sum_c' W_cb[c][c']*vmT[l][c'] + b_c[c])  (M=1024,N=2048,K=1024)
    gemm_tn<__bf16, 1, true><<<dim3(16, 8), 256, 0, stream>>>(W_cb, vmT, b_c, vmr, 1024, 2048, 1024);
    // T4: vmrT[l][c] <- vmr (1024x2048 bf16)
    transpose_b16<<<dim3(64, 32), tb, 0, stream>>>(vmr, vmrT, 1024, 2048);
    // G4: vma1T[l][c] = sum_k ST[l][k]*vmr[c][k]   (M=2048,N=1024,K=2048)
    gemm_tn<__bf16, 0, false><<<dim3(8, 16), 256, 0, stream>>>(ST, vmr, nullptr, vma1T, 2048, 1024, 2048);
    // C3: W_madb <- W_mad
    cast_bf16<<<dim3(1024), 256, 0, stream>>>(W_mad, W_madb, 1024 * 1024);
    // G5: vmaT[l][c] = sum_c' vma1T[l][c']*W_madb[c][c'] + b_mad[c]  (M=2048,N=1024,K=1024)
    gemm_tn<__bf16, 2, false><<<dim3(8, 16), 256, 0, stream>>>(vma1T, W_madb, b_mad, vmaT, 2048, 1024, 1024);
    // T3: W_gcnT[c][c'] <- W_gcn (1024x1024 fp32)
    transpose_cast_bf16<<<dim3(32, 32), tb, 0, stream>>>(W_gcn, W_gcnT, 1024, 1024);
    // G6: P[k][l] = sum_c vmaT[k][c]*vmaT[l][c]   (M=2048,N=2048,K=1024)
    gemm_tn<__bf16, 0, false><<<dim3(16, 16), 256, 0, stream>>>(vmaT, vmaT, nullptr, P, 2048, 2048, 1024);
    // SM2: softmax over l (rows of P)
    row_softmax_bf16<<<dim3(2048), 256, 0, stream>>>(P);
    // G7: xT[c][l] = sum_c' W_gcnT[c][c']*vmrT[l][c'] + b_gcn[c]  (M=1024,N=2048,K=1024)
    gemm_tn<__bf16, 1, false><<<dim3(16, 8), 256, 0, stream>>>(W_gcnT, vmrT, b_gcn, xT, 1024, 2048, 1024);
    // G9: out0[k][c] = sum_l P[k][l]*xT[c][l]   (M=2048,N=1024,K=2048), fp32 out
    gemm_tn<float, 0, false><<<dim3(8, 16), 256, 0, stream>>>(P, xT, nullptr, out0, 2048, 1024, 2048);
    // T5: out[c][pos] = out0[pos][c]
    transpose_f32<<<dim3(32, 64), tb, 0, stream>>>(out0, out, 2048, 1024);
}

// Round 7
// 292.501 us; speedup vs baseline: 3.0738x; 1.0249x over previous
//
#include <hip/hip_runtime.h>
#include <hip/hip_bf16.h>

// CHNN=1024, K=L=2048. Inputs fp32, output fp32. bf16 MFMA GEMMs (16x16x32),
// fp32 accumulation, TN layout (both operands k-contiguous).
// Round 7: global_load_lds async staging, full 256-block grids via FMxFN tile
// templates, fused transpose epilogues (STORE_MODE), batched prep kernels.
// Workspace: exactly 32 MB (proven available in round 5).

typedef __bf16 bf16x4 __attribute__((ext_vector_type(4)));
typedef __bf16 bf16x8 __attribute__((ext_vector_type(8)));
typedef float  f32x4  __attribute__((ext_vector_type(4)));

typedef const void __attribute__((address_space(1)))* gptr_t;
typedef void       __attribute__((address_space(3)))* lptr_t;

__device__ __forceinline__ void load16_lds(const __bf16* g, __bf16* l)
{
    // async global->LDS, 16B per lane; LDS dest = wave-uniform base + lane*16
    __builtin_amdgcn_global_load_lds((gptr_t)g, (lptr_t)l, 16, 0, 0);
}

// ---------------- MFMA TN GEMM ----------------
// C(M,N) = A(M,K) * B(N,K)^T, A/B bf16 k-contiguous.
// Tile: TM=FM*32 x TN=FN*32, 4 waves in 2x2, wave tile FM*16 x FN*16 frags.
// BIAS_MODE: 0 none, 1 bias[m], 2 bias[n].
// STORE_MODE: 0 C[m][n], 1 CT[n][m] (vectorized over m), 2 both.
template<typename OUT_T, int FM, int FN, int BIAS_MODE, bool RELU, int STORE_MODE>
__global__ __launch_bounds__(256)
void gemm_tn(const __bf16* __restrict__ A, const __bf16* __restrict__ B,
             const float* __restrict__ bias,
             OUT_T* __restrict__ C, OUT_T* __restrict__ CT,
             int M, int N, int K)
{
    constexpr int TM = FM * 32, TN = FN * 32;
    constexpr int NA = TM / 64, NB = TN / 64;   // global_load_lds instrs per wave
    __shared__ __bf16 sA[TM * 32];
    __shared__ __bf16 sB[TN * 32];
    const int tid = threadIdx.x, lane = tid & 63, wv = tid >> 6;
    const int m0 = blockIdx.y * TM, n0 = blockIdx.x * TN;
    const int mw = (wv >> 1) * (FM * 16), nw = (wv & 1) * (FN * 16);

    f32x4 acc[FM][FN];
    #pragma unroll
    for (int i = 0; i < FM; ++i)
        #pragma unroll
        for (int j = 0; j < FN; ++j)
            acc[i][j] = (f32x4){0.f, 0.f, 0.f, 0.f};

    const __bf16* gA = A + (size_t)m0 * K;
    const __bf16* gB = B + (size_t)n0 * K;

    for (int k0 = 0; k0 < K; k0 += 32) {
        // stage tile k0: 16B chunk c covers row c>>2, bf16 k-offset (c&3)*8
        #pragma unroll
        for (int i = 0; i < NA; ++i) {
            const int c = (wv * NA + i) * 64 + lane;
            load16_lds(gA + (size_t)(c >> 2) * K + k0 + (c & 3) * 8,
                       &sA[(wv * NA + i) * 512]);
        }
        #pragma unroll
        for (int i = 0; i < NB; ++i) {
            const int c = (wv * NB + i) * 64 + lane;
            load16_lds(gB + (size_t)(c >> 2) * K + k0 + (c & 3) * 8,
                       &sB[(wv * NB + i) * 512]);
        }
        __syncthreads();               // drains vmcnt (compiler) + barrier
        bf16x8 af[FM], bfr[FN];
        #pragma unroll
        for (int i = 0; i < FM; ++i)
            af[i] = *(const bf16x8*)&sA[(mw + i * 16 + (lane & 15)) * 32 + (lane >> 4) * 8];
        #pragma unroll
        for (int j = 0; j < FN; ++j)
            bfr[j] = *(const bf16x8*)&sB[(nw + j * 16 + (lane & 15)) * 32 + (lane >> 4) * 8];
        #pragma unroll
        for (int i = 0; i < FM; ++i)
            #pragma unroll
            for (int j = 0; j < FN; ++j)
                acc[i][j] = __builtin_amdgcn_mfma_f32_16x16x32_bf16(af[i], bfr[j], acc[i][j], 0, 0, 0);
        __syncthreads();               // frags consumed; LDS may be overwritten
    }

    // Epilogue. C/D layout: col=lane&15, row=(lane>>4)*4+reg (verified r6).
    #pragma unroll
    for (int i = 0; i < FM; ++i) {
        const int rowb = m0 + mw + i * 16 + (lane >> 4) * 4;
        #pragma unroll
        for (int j = 0; j < FN; ++j) {
            const int col = n0 + nw + j * 16 + (lane & 15);
            f32x4 v = acc[i][j];
            #pragma unroll
            for (int r = 0; r < 4; ++r) {
                float f = v[r];
                if (BIAS_MODE == 1) f += bias[rowb + r];
                if (BIAS_MODE == 2) f += bias[col];
                if (RELU) f = fmaxf(f, 0.f);
                v[r] = f;
            }
            if (STORE_MODE == 0 || STORE_MODE == 2) {
                #pragma unroll
                for (int r = 0; r < 4; ++r)
                    C[(size_t)(rowb + r) * N + col] = (OUT_T)v[r];
            }
            if (STORE_MODE == 1 || STORE_MODE == 2) {
                if constexpr (sizeof(OUT_T) == 4) {
                    *(f32x4*)&CT[(size_t)col * M + rowb] = v;
                } else {
                    bf16x4 w = { (__bf16)v[0], (__bf16)v[1], (__bf16)v[2], (__bf16)v[3] };
                    *(bf16x4*)&CT[(size_t)col * M + rowb] = w;
                }
            }
        }
    }
}

// ---------------- helpers ----------------
// z-batched fp32->bf16 transpose-cast: z=0: vc->vcT, z=1: vm->vmT (1024x2048).
__global__ __launch_bounds__(256)
void transpose_cast2(const float* __restrict__ s0, __bf16* __restrict__ d0,
                     const float* __restrict__ s1, __bf16* __restrict__ d1)
{
    const float* in  = blockIdx.z ? s1 : s0;
    __bf16*      outp = blockIdx.z ? d1 : d0;
    const int R = 1024, C = 2048;
    __shared__ float t[32][33];
    const int bx = blockIdx.x * 32, by = blockIdx.y * 32;
    const int tx = threadIdx.x, ty = threadIdx.y;
    #pragma unroll
    for (int i = ty; i < 32; i += 8)
        t[i][tx] = in[(size_t)(by + i) * C + (bx + tx)];
    __syncthreads();
    #pragma unroll
    for (int i = ty; i < 32; i += 8)
        outp[(size_t)(bx + i) * R + (by + tx)] = (__bf16)t[tx][i];
}

// single fp32->bf16 transpose-cast (for W_gcn, 1024x1024)
__global__ __launch_bounds__(256)
void transpose_cast1(const float* __restrict__ in, __bf16* __restrict__ outp, int R, int C)
{
    __shared__ float t[32][33];
    const int bx = blockIdx.x * 32, by = blockIdx.y * 32;
    const int tx = threadIdx.x, ty = threadIdx.y;
    #pragma unroll
    for (int i = ty; i < 32; i += 8)
        t[i][tx] = in[(size_t)(by + i) * C + (bx + tx)];
    __syncthreads();
    #pragma unroll
    for (int i = ty; i < 32; i += 8)
        outp[(size_t)(bx + i) * R + (by + tx)] = (__bf16)t[tx][i];
}

// z-batched fp32->bf16 casts (W_ak 2M, W_c 1M, W_mad 1M elems).
__global__ __launch_bounds__(256)
void cast3(const float* __restrict__ s0, __bf16* __restrict__ d0, int n0,
           const float* __restrict__ s1, __bf16* __restrict__ d1, int n1,
           const float* __restrict__ s2, __bf16* __restrict__ d2, int n2)
{
    const float* s; __bf16* d; int n;
    if (blockIdx.z == 0)      { s = s0; d = d0; n = n0; }
    else if (blockIdx.z == 1) { s = s1; d = d1; n = n1; }
    else                      { s = s2; d = d2; n = n2; }
    const int i = (blockIdx.x * 256 + threadIdx.x) * 4;
    if (i >= n) return;
    float4 v = *(const float4*)&s[i];
    bf16x4 w = { (__bf16)v.x, (__bf16)v.y, (__bf16)v.z, (__bf16)v.w };
    *(bf16x4*)&d[i] = w;
}

// In-place row softmax over N=2048 bf16; one block per row, 8 elems/thread.
__global__ __launch_bounds__(256)
void row_softmax_bf16(__bf16* __restrict__ A)
{
    __shared__ float red[256];
    const int t = threadIdx.x;
    __bf16* p = A + (size_t)blockIdx.x * 2048;
    bf16x8 v = *(bf16x8*)&p[t * 8];
    float f[8];
    float m = -1e30f;
    #pragma unroll
    for (int r = 0; r < 8; ++r) { f[r] = (float)v[r]; m = fmaxf(m, f[r]); }
    red[t] = m;
    __syncthreads();
    for (int s = 128; s > 0; s >>= 1) {
        if (t < s) red[t] = fmaxf(red[t], red[t + s]);
        __syncthreads();
    }
    m = red[0];
    __syncthreads();
    float sum = 0.f;
    #pragma unroll
    for (int r = 0; r < 8; ++r) { f[r] = expf(f[r] - m); sum += f[r]; }
    red[t] = sum;
    __syncthreads();
    for (int s = 128; s > 0; s >>= 1) {
        if (t < s) red[t] += red[t + s];
        __syncthreads();
    }
    const float inv = 1.f / red[0];
    bf16x8 w;
    #pragma unroll
    for (int r = 0; r < 8; ++r) w[r] = (__bf16)(f[r] * inv);
    *(bf16x8*)&p[t * 8] = w;
}

extern "C" void kernel_launch(void* const* d_in, const int* in_sizes, int n_in,
                              void* d_out, int out_size, void* d_ws, size_t ws_size,
                              hipStream_t stream)
{
    const float* vc    = (const float*)d_in[0];
    const float* vm    = (const float*)d_in[1];
    const float* W_ak  = (const float*)d_in[2];
    const float* b_ak  = (const float*)d_in[3];
    const float* W_c   = (const float*)d_in[4];
    const float* b_c   = (const float*)d_in[5];
    const float* W_mad = (const float*)d_in[6];
    const float* b_mad = (const float*)d_in[7];
    const float* W_gcn = (const float*)d_in[8];
    const float* b_gcn = (const float*)d_in[9];
    float* out = (float*)d_out;

    // Arena, 32 MB exactly. Liveness (step numbers = launch order below):
    //  [0,8):   ST (w3, r4,7)      -> P (w9, sm10, r12)
    //  [8,12):  vcT (w1, r3)       -> vma1T (w7, r8)
    //  [12,16): W_akb (w2, r3)     -> vmaT (w8, r9)
    //  [16,20): vmT (w1, r5)       -> xT (w11, r12)
    //  [20,24): vmr (w5, r7)
    //  [24,28): vmrT (w5, r11)
    //  [28,30): W_cb (w2, r5)      -> W_gcnT (w6, r11)
    //  [30,32): W_madb (w2, r8)
    char* ws = (char*)d_ws;
    const size_t MB = 1u << 20;
    __bf16* ST     = (__bf16*)(ws);
    __bf16* P      = (__bf16*)(ws);
    __bf16* vcT    = (__bf16*)(ws + 8 * MB);
    __bf16* vma1T  = (__bf16*)(ws + 8 * MB);
    __bf16* W_akb  = (__bf16*)(ws + 12 * MB);
    __bf16* vmaT   = (__bf16*)(ws + 12 * MB);
    __bf16* vmT    = (__bf16*)(ws + 16 * MB);
    __bf16* xT     = (__bf16*)(ws + 16 * MB);
    __bf16* vmr    = (__bf16*)(ws + 20 * MB);
    __bf16* vmrT   = (__bf16*)(ws + 24 * MB);
    __bf16* W_cb   = (__bf16*)(ws + 28 * MB);
    __bf16* W_gcnT = (__bf16*)(ws + 28 * MB);
    __bf16* W_madb = (__bf16*)(ws + 30 * MB);

    // 1. vcT[l][c] <- vc ; vmT[l][c] <- vm
    transpose_cast2<<<dim3(64, 32, 2), dim3(32, 8), 0, stream>>>(vc, vcT, vm, vmT);
    // 2. W_akb <- W_ak (2M), W_cb <- W_c (1M), W_madb <- W_mad (1M)
    cast3<<<dim3(2048, 1, 3), 256, 0, stream>>>(W_ak, W_akb, 2048 * 1024,
                                                W_c, W_cb, 1024 * 1024,
                                                W_mad, W_madb, 1024 * 1024);
    // 3. ST[l][k] = vcT·W_akb + b_ak[k]      (M=2048,N=2048,K=1024)
    gemm_tn<__bf16, 4, 4, 2, false, 0><<<dim3(16, 16), 256, 0, stream>>>(
        vcT, W_akb, b_ak, ST, nullptr, 2048, 2048, 1024);
    // 4. softmax over k (rows of ST)
    row_softmax_bf16<<<dim3(2048), 256, 0, stream>>>(ST);
    // 5. vmr[c][l], vmrT[l][c] = relu(W_cb·vmT + b_c[c])  (M=1024,N=2048,K=1024)
    gemm_tn<__bf16, 2, 4, 1, true, 2><<<dim3(16, 16), 256, 0, stream>>>(
        W_cb, vmT, b_c, vmr, vmrT, 1024, 2048, 1024);
    // 6. W_gcnT[c][c'] <- W_gcn (into W_cb's dead slot)
    transpose_cast1<<<dim3(32, 32), dim3(32, 8), 0, stream>>>(W_gcn, W_gcnT, 1024, 1024);
    // 7. vma1T[l][c] = ST·vmr               (M=2048,N=1024,K=2048)
    gemm_tn<__bf16, 4, 2, 0, false, 0><<<dim3(16, 16), 256, 0, stream>>>(
        ST, vmr, nullptr, vma1T, nullptr, 2048, 1024, 2048);
    // 8. vmaT[l][c] = vma1T·W_madb + b_mad[c]  (M=2048,N=1024,K=1024)
    gemm_tn<__bf16, 4, 2, 2, false, 0><<<dim3(16, 16), 256, 0, stream>>>(
        vma1T, W_madb, b_mad, vmaT, nullptr, 2048, 1024, 1024);
    // 9. P[k][l] = vmaT·vmaT               (M=2048,N=2048,K=1024)
    gemm_tn<__bf16, 4, 4, 0, false, 0><<<dim3(16, 16), 256, 0, stream>>>(
        vmaT, vmaT, nullptr, P, nullptr, 2048, 2048, 1024);
    // 10. softmax over l (rows of P)
    row_softmax_bf16<<<dim3(2048), 256, 0, stream>>>(P);
    // 11. xT[c][l] = W_gcnT·vmrT + b_gcn[c]  (M=1024,N=2048,K=1024)
    gemm_tn<__bf16, 2, 4, 1, false, 0><<<dim3(16, 16), 256, 0, stream>>>(
        W_gcnT, vmrT, b_gcn, xT, nullptr, 1024, 2048, 1024);
    // 12. out[c][pos] = (P·xT)^T            (M=2048,N=1024,K=2048), fp32, direct
    gemm_tn<float, 4, 2, 0, false, 1><<<dim3(16, 16), 256, 0, stream>>>(
        P, xT, nullptr, nullptr, out, 2048, 1024, 2048);
}

// Round 8
// 255.740 us; speedup vs baseline: 3.5156x; 1.1437x over previous
//
#include <hip/hip_runtime.h>
#include <hip/hip_bf16.h>

// CHNN=1024, K=L=2048. Inputs fp32, output fp32. bf16 MFMA GEMMs (16x16x32),
// fp32 accumulation, TN layout (both operands k-contiguous).
// Round 8: fix 1-block/CU starvation (r7's real bottleneck): TMxTN tiles sized
// so every GEMM launches 512 blocks (2 blocks/CU, 2 waves/SIMD), plus LDS
// double-buffering with one barrier per K-step (loads for k+1 issued before
// compute of k, so the vmcnt(0)-before-barrier drain lands after compute).

typedef __bf16 bf16x4 __attribute__((ext_vector_type(4)));
typedef __bf16 bf16x8 __attribute__((ext_vector_type(8)));
typedef float  f32x4  __attribute__((ext_vector_type(4)));

typedef const void __attribute__((address_space(1)))* gptr_t;
typedef void       __attribute__((address_space(3)))* lptr_t;

__device__ __forceinline__ void load16_lds(const __bf16* g, __bf16* l)
{
    // async global->LDS, 16B/lane; LDS dest = wave-uniform base + lane*16
    __builtin_amdgcn_global_load_lds((gptr_t)g, (lptr_t)l, 16, 0, 0);
}

// ---------------- MFMA TN GEMM ----------------
// C(M,N) = A(M,K) * B(N,K)^T, A/B bf16 k-contiguous. BK=32.
// 4 waves in 2x2; wave tile (TM/2)x(TN/2) as FMxFN 16x16 fragments.
// BIAS_MODE: 0 none, 1 bias[m], 2 bias[n].
// STORE_MODE: 0 C[m][n], 1 CT[n][m] (16B vectors over m), 2 both.
template<typename OUT_T, int TM, int TN, int BIAS_MODE, bool RELU, int STORE_MODE>
__global__ __launch_bounds__(256, 2)
void gemm_tn(const __bf16* __restrict__ A, const __bf16* __restrict__ B,
             const float* __restrict__ bias,
             OUT_T* __restrict__ C, OUT_T* __restrict__ CT,
             int M, int N, int K)
{
    constexpr int FM = TM / 32, FN = TN / 32;
    constexpr int NA = TM / 64, NB = TN / 64;   // global_load_lds per wave per tile
    __shared__ __bf16 sA[2][TM * 32];
    __shared__ __bf16 sB[2][TN * 32];
    const int tid = threadIdx.x, lane = tid & 63, wv = tid >> 6;
    const int m0 = blockIdx.y * TM, n0 = blockIdx.x * TN;
    const int mw = (wv >> 1) * (FM * 16), nw = (wv & 1) * (FN * 16);

    f32x4 acc[FM][FN];
    #pragma unroll
    for (int i = 0; i < FM; ++i)
        #pragma unroll
        for (int j = 0; j < FN; ++j)
            acc[i][j] = (f32x4){0.f, 0.f, 0.f, 0.f};

    const __bf16* gA = A + (size_t)m0 * K;
    const __bf16* gB = B + (size_t)n0 * K;

    // stage tile k0 into buffer `buf`: 16B chunk c = row c>>2, k-offset (c&3)*8
    auto stage = [&](int k0, int buf) {
        #pragma unroll
        for (int i = 0; i < NA; ++i) {
            const int c = (wv * NA + i) * 64 + lane;
            load16_lds(gA + (size_t)(c >> 2) * K + k0 + (c & 3) * 8,
                       &sA[buf][(wv * NA + i) * 512]);
        }
        #pragma unroll
        for (int i = 0; i < NB; ++i) {
            const int c = (wv * NB + i) * 64 + lane;
            load16_lds(gB + (size_t)(c >> 2) * K + k0 + (c & 3) * 8,
                       &sB[buf][(wv * NB + i) * 512]);
        }
    };

    stage(0, 0);
    int cur = 0;
    for (int k0 = 0; k0 < K; k0 += 32) {
        __syncthreads();                       // buf[cur] loads drained here
        if (k0 + 32 < K) stage(k0 + 32, cur ^ 1);   // prefetch next tile
        bf16x8 af[FM], bfr[FN];
        #pragma unroll
        for (int i = 0; i < FM; ++i)
            af[i] = *(const bf16x8*)&sA[cur][(mw + i * 16 + (lane & 15)) * 32 + (lane >> 4) * 8];
        #pragma unroll
        for (int j = 0; j < FN; ++j)
            bfr[j] = *(const bf16x8*)&sB[cur][(nw + j * 16 + (lane & 15)) * 32 + (lane >> 4) * 8];
        #pragma unroll
        for (int i = 0; i < FM; ++i)
            #pragma unroll
            for (int j = 0; j < FN; ++j)
                acc[i][j] = __builtin_amdgcn_mfma_f32_16x16x32_bf16(af[i], bfr[j], acc[i][j], 0, 0, 0);
        cur ^= 1;
    }

    // Epilogue. C/D layout: col=lane&15, row=(lane>>4)*4+reg (verified r6/r7).
    #pragma unroll
    for (int i = 0; i < FM; ++i) {
        const int rowb = m0 + mw + i * 16 + (lane >> 4) * 4;
        #pragma unroll
        for (int j = 0; j < FN; ++j) {
            const int col = n0 + nw + j * 16 + (lane & 15);
            f32x4 v = acc[i][j];
            #pragma unroll
            for (int r = 0; r < 4; ++r) {
                float f = v[r];
                if (BIAS_MODE == 1) f += bias[rowb + r];
                if (BIAS_MODE == 2) f += bias[col];
                if (RELU) f = fmaxf(f, 0.f);
                v[r] = f;
            }
            if (STORE_MODE == 0 || STORE_MODE == 2) {
                #pragma unroll
                for (int r = 0; r < 4; ++r)
                    C[(size_t)(rowb + r) * N + col] = (OUT_T)v[r];
            }
            if (STORE_MODE == 1 || STORE_MODE == 2) {
                if constexpr (sizeof(OUT_T) == 4) {
                    *(f32x4*)&CT[(size_t)col * M + rowb] = v;
                } else {
                    bf16x4 w = { (__bf16)v[0], (__bf16)v[1], (__bf16)v[2], (__bf16)v[3] };
                    *(bf16x4*)&CT[(size_t)col * M + rowb] = w;
                }
            }
        }
    }
}

// ---------------- helpers ----------------
// z-batched fp32->bf16 transpose-cast: z=0: vc->vcT, z=1: vm->vmT (1024x2048).
__global__ __launch_bounds__(256)
void transpose_cast2(const float* __restrict__ s0, __bf16* __restrict__ d0,
                     const float* __restrict__ s1, __bf16* __restrict__ d1)
{
    const float* in   = blockIdx.z ? s1 : s0;
    __bf16*      outp = blockIdx.z ? d1 : d0;
    const int R = 1024, C = 2048;
    __shared__ float t[32][33];
    const int bx = blockIdx.x * 32, by = blockIdx.y * 32;
    const int tx = threadIdx.x, ty = threadIdx.y;
    #pragma unroll
    for (int i = ty; i < 32; i += 8)
        t[i][tx] = in[(size_t)(by + i) * C + (bx + tx)];
    __syncthreads();
    #pragma unroll
    for (int i = ty; i < 32; i += 8)
        outp[(size_t)(bx + i) * R + (by + tx)] = (__bf16)t[tx][i];
}

// single fp32->bf16 transpose-cast (for W_gcn, 1024x1024)
__global__ __launch_bounds__(256)
void transpose_cast1(const float* __restrict__ in, __bf16* __restrict__ outp, int R, int C)
{
    __shared__ float t[32][33];
    const int bx = blockIdx.x * 32, by = blockIdx.y * 32;
    const int tx = threadIdx.x, ty = threadIdx.y;
    #pragma unroll
    for (int i = ty; i < 32; i += 8)
        t[i][tx] = in[(size_t)(by + i) * C + (bx + tx)];
    __syncthreads();
    #pragma unroll
    for (int i = ty; i < 32; i += 8)
        outp[(size_t)(bx + i) * R + (by + tx)] = (__bf16)t[tx][i];
}

// z-batched fp32->bf16 casts (W_ak 2M, W_c 1M, W_mad 1M elems).
__global__ __launch_bounds__(256)
void cast3(const float* __restrict__ s0, __bf16* __restrict__ d0, int n0,
           const float* __restrict__ s1, __bf16* __restrict__ d1, int n1,
           const float* __restrict__ s2, __bf16* __restrict__ d2, int n2)
{
    const float* s; __bf16* d; int n;
    if (blockIdx.z == 0)      { s = s0; d = d0; n = n0; }
    else if (blockIdx.z == 1) { s = s1; d = d1; n = n1; }
    else                      { s = s2; d = d2; n = n2; }
    const int i = (blockIdx.x * 256 + threadIdx.x) * 4;
    if (i >= n) return;
    float4 v = *(const float4*)&s[i];
    bf16x4 w = { (__bf16)v.x, (__bf16)v.y, (__bf16)v.z, (__bf16)v.w };
    *(bf16x4*)&d[i] = w;
}

// In-place row softmax over N=2048 bf16; one block per row, 8 elems/thread.
__global__ __launch_bounds__(256)
void row_softmax_bf16(__bf16* __restrict__ A)
{
    __shared__ float red[256];
    const int t = threadIdx.x;
    __bf16* p = A + (size_t)blockIdx.x * 2048;
    bf16x8 v = *(bf16x8*)&p[t * 8];
    float f[8];
    float m = -1e30f;
    #pragma unroll
    for (int r = 0; r < 8; ++r) { f[r] = (float)v[r]; m = fmaxf(m, f[r]); }
    red[t] = m;
    __syncthreads();
    for (int s = 128; s > 0; s >>= 1) {
        if (t < s) red[t] = fmaxf(red[t], red[t + s]);
        __syncthreads();
    }
    m = red[0];
    __syncthreads();
    float sum = 0.f;
    #pragma unroll
    for (int r = 0; r < 8; ++r) { f[r] = expf(f[r] - m); sum += f[r]; }
    red[t] = sum;
    __syncthreads();
    for (int s = 128; s > 0; s >>= 1) {
        if (t < s) red[t] += red[t + s];
        __syncthreads();
    }
    const float inv = 1.f / red[0];
    bf16x8 w;
    #pragma unroll
    for (int r = 0; r < 8; ++r) w[r] = (__bf16)(f[r] * inv);
    *(bf16x8*)&p[t * 8] = w;
}

extern "C" void kernel_launch(void* const* d_in, const int* in_sizes, int n_in,
                              void* d_out, int out_size, void* d_ws, size_t ws_size,
                              hipStream_t stream)
{
    const float* vc    = (const float*)d_in[0];
    const float* vm    = (const float*)d_in[1];
    const float* W_ak  = (const float*)d_in[2];
    const float* b_ak  = (const float*)d_in[3];
    const float* W_c   = (const float*)d_in[4];
    const float* b_c   = (const float*)d_in[5];
    const float* W_mad = (const float*)d_in[6];
    const float* b_mad = (const float*)d_in[7];
    const float* W_gcn = (const float*)d_in[8];
    const float* b_gcn = (const float*)d_in[9];
    float* out = (float*)d_out;

    // Arena, 32 MB exactly. Liveness (step numbers = launch order below):
    //  [0,8):   ST (w3, r4,7)      -> P (w9, sm10, r12)
    //  [8,12):  vcT (w1, r3)       -> vma1T (w7, r8)
    //  [12,16): W_akb (w2, r3)     -> vmaT (w8, r9)
    //  [16,20): vmT (w1, r5)       -> xT (w11, r12)
    //  [20,24): vmr (w5, r7)
    //  [24,28): vmrT (w5, r11)
    //  [28,30): W_cb (w2, r5)      -> W_gcnT (w6, r11)
    //  [30,32): W_madb (w2, r8)
    char* ws = (char*)d_ws;
    const size_t MB = 1u << 20;
    __bf16* ST     = (__bf16*)(ws);
    __bf16* P      = (__bf16*)(ws);
    __bf16* vcT    = (__bf16*)(ws + 8 * MB);
    __bf16* vma1T  = (__bf16*)(ws + 8 * MB);
    __bf16* W_akb  = (__bf16*)(ws + 12 * MB);
    __bf16* vmaT   = (__bf16*)(ws + 12 * MB);
    __bf16* vmT    = (__bf16*)(ws + 16 * MB);
    __bf16* xT     = (__bf16*)(ws + 16 * MB);
    __bf16* vmr    = (__bf16*)(ws + 20 * MB);
    __bf16* vmrT   = (__bf16*)(ws + 24 * MB);
    __bf16* W_cb   = (__bf16*)(ws + 28 * MB);
    __bf16* W_gcnT = (__bf16*)(ws + 28 * MB);
    __bf16* W_madb = (__bf16*)(ws + 30 * MB);

    // 1. vcT[l][c] <- vc ; vmT[l][c] <- vm
    transpose_cast2<<<dim3(64, 32, 2), dim3(32, 8), 0, stream>>>(vc, vcT, vm, vmT);
    // 2. W_akb <- W_ak (2M), W_cb <- W_c (1M), W_madb <- W_mad (1M)
    cast3<<<dim3(2048, 1, 3), 256, 0, stream>>>(W_ak, W_akb, 2048 * 1024,
                                                W_c, W_cb, 1024 * 1024,
                                                W_mad, W_madb, 1024 * 1024);
    // 3. ST[l][k] = vcT·W_akb + b_ak[k]      (M=2048,N=2048,K=1024) 128x64 -> 512 blk
    gemm_tn<__bf16, 128, 64, 2, false, 0><<<dim3(32, 16), 256, 0, stream>>>(
        vcT, W_akb, b_ak, ST, nullptr, 2048, 2048, 1024);
    // 4. softmax over k (rows of ST)
    row_softmax_bf16<<<dim3(2048), 256, 0, stream>>>(ST);
    // 5. vmr[c][l], vmrT[l][c] = relu(W_cb·vmT + b_c[c])  (M=1024,N=2048,K=1024) 64x64
    gemm_tn<__bf16, 64, 64, 1, true, 2><<<dim3(32, 16), 256, 0, stream>>>(
        W_cb, vmT, b_c, vmr, vmrT, 1024, 2048, 1024);
    // 6. W_gcnT[c][c'] <- W_gcn (into W_cb's dead slot)
    transpose_cast1<<<dim3(32, 32), dim3(32, 8), 0, stream>>>(W_gcn, W_gcnT, 1024, 1024);
    // 7. vma1T[l][c] = ST·vmr               (M=2048,N=1024,K=2048) 64x64 -> 512 blk
    gemm_tn<__bf16, 64, 64, 0, false, 0><<<dim3(16, 32), 256, 0, stream>>>(
        ST, vmr, nullptr, vma1T, nullptr, 2048, 1024, 2048);
    // 8. vmaT[l][c] = vma1T·W_madb + b_mad[c]  (M=2048,N=1024,K=1024) 64x64
    gemm_tn<__bf16, 64, 64, 2, false, 0><<<dim3(16, 32), 256, 0, stream>>>(
        vma1T, W_madb, b_mad, vmaT, nullptr, 2048, 1024, 1024);
    // 9. P[k][l] = vmaT·vmaT               (M=2048,N=2048,K=1024) 128x64 -> 512 blk
    gemm_tn<__bf16, 128, 64, 0, false, 0><<<dim3(32, 16), 256, 0, stream>>>(
        vmaT, vmaT, nullptr, P, nullptr, 2048, 2048, 1024);
    // 10. softmax over l (rows of P)
    row_softmax_bf16<<<dim3(2048), 256, 0, stream>>>(P);
    // 11. xT[c][l] = W_gcnT·vmrT + b_gcn[c]  (M=1024,N=2048,K=1024) 64x64
    gemm_tn<__bf16, 64, 64, 1, false, 0><<<dim3(32, 16), 256, 0, stream>>>(
        W_gcnT, vmrT, b_gcn, xT, nullptr, 1024, 2048, 1024);
    // 12. out[c][pos] = (P·xT)^T            (M=2048,N=1024,K=2048) 64x64, fp32 direct
    gemm_tn<float, 64, 64, 0, false, 1><<<dim3(16, 32), 256, 0, stream>>>(
        P, xT, nullptr, nullptr, out, 2048, 1024, 2048);
}

// Round 9
// 223.414 us; speedup vs baseline: 4.0243x; 1.1447x over previous
//
#include <hip/hip_runtime.h>
#include <hip/hip_bf16.h>

// CHNN=1024, K=L=2048. Inputs fp32, output fp32. bf16 MFMA GEMMs (16x16x32),
// fp32 accumulation, TN layout (k-contiguous operands), dbuf LDS + async
// global_load_lds staging. Round 9: the inner loop is at the m97-structure's
// measured small-shape plateau (~300 TF at N<=2048, m102), so this round
// attacks launch structure instead: independent GEMMs fused into single
// launches (G3+G5 = 384 blk, G7+G11 = 256 blk), 128x64 tiles for G8/G12
// (256 blk), prep kernels batched. 12 -> 8 launches.

typedef __bf16 bf16x4 __attribute__((ext_vector_type(4)));
typedef __bf16 bf16x8 __attribute__((ext_vector_type(8)));
typedef float  f32x4  __attribute__((ext_vector_type(4)));

typedef const void __attribute__((address_space(1)))* gptr_t;
typedef void       __attribute__((address_space(3)))* lptr_t;

__device__ __forceinline__ void load16_lds(const __bf16* g, __bf16* l)
{
    // async global->LDS, 16B/lane; LDS dest = wave-uniform base + lane*16
    __builtin_amdgcn_global_load_lds((gptr_t)g, (lptr_t)l, 16, 0, 0);
}

// ---------------- GEMM config + body ----------------
template<typename OT, int TM_, int TN_, int BIAS_, bool RELU_, int STORE_>
struct GC {
    using OUT_T = OT;
    static constexpr int TM = TM_, TN = TN_, BIAS = BIAS_, STORE = STORE_;
    static constexpr bool RELU = RELU_;
    static constexpr int SMEM = 2 * (TM_ + TN_) * 32 * 2;   // dbuf, bf16
};

// C(M,N) = A(M,K)*B(N,K)^T; A,B bf16 k-contiguous; BK=32; 4 waves 2x2.
// BIAS: 0 none, 1 bias[row], 2 bias[col]. STORE: 0 C[m][n], 1 CT[n][m], 2 both.
template<class CF>
__device__ __forceinline__ void gemm_body(
    int bid, char* smem,
    const __bf16* __restrict__ A, const __bf16* __restrict__ B,
    const float* __restrict__ bias,
    typename CF::OUT_T* __restrict__ C, typename CF::OUT_T* __restrict__ CT,
    int M, int N, int K, int ntx)
{
    constexpr int TM = CF::TM, TN = CF::TN;
    constexpr int FM = TM / 32, FN = TN / 32;
    constexpr int NA = TM / 64, NB = TN / 64;
    __bf16* sA = (__bf16*)smem;                  // [2][TM*32]
    __bf16* sB = (__bf16*)smem + 2 * TM * 32;    // [2][TN*32]
    const int tid = threadIdx.x, lane = tid & 63, wv = tid >> 6;
    const int m0 = (bid / ntx) * TM, n0 = (bid % ntx) * TN;
    const int mw = (wv >> 1) * (FM * 16), nw = (wv & 1) * (FN * 16);

    f32x4 acc[FM][FN];
    #pragma unroll
    for (int i = 0; i < FM; ++i)
        #pragma unroll
        for (int j = 0; j < FN; ++j)
            acc[i][j] = (f32x4){0.f, 0.f, 0.f, 0.f};

    const __bf16* gA = A + (size_t)m0 * K;
    const __bf16* gB = B + (size_t)n0 * K;

    auto stage = [&](int k0, int buf) {
        #pragma unroll
        for (int i = 0; i < NA; ++i) {
            const int c = (wv * NA + i) * 64 + lane;   // 16B chunk id
            load16_lds(gA + (size_t)(c >> 2) * K + k0 + (c & 3) * 8,
                       &sA[buf * TM * 32 + (wv * NA + i) * 512]);
        }
        #pragma unroll
        for (int i = 0; i < NB; ++i) {
            const int c = (wv * NB + i) * 64 + lane;
            load16_lds(gB + (size_t)(c >> 2) * K + k0 + (c & 3) * 8,
                       &sB[buf * TN * 32 + (wv * NB + i) * 512]);
        }
    };

    stage(0, 0);
    int cur = 0;
    for (int k0 = 0; k0 < K; k0 += 32) {
        __syncthreads();                          // buf[cur] staged (vmcnt drain)
        if (k0 + 32 < K) stage(k0 + 32, cur ^ 1); // prefetch next
        bf16x8 af[FM], bfr[FN];
        #pragma unroll
        for (int i = 0; i < FM; ++i)
            af[i] = *(const bf16x8*)&sA[cur * TM * 32 + (mw + i * 16 + (lane & 15)) * 32 + (lane >> 4) * 8];
        #pragma unroll
        for (int j = 0; j < FN; ++j)
            bfr[j] = *(const bf16x8*)&sB[cur * TN * 32 + (nw + j * 16 + (lane & 15)) * 32 + (lane >> 4) * 8];
        #pragma unroll
        for (int i = 0; i < FM; ++i)
            #pragma unroll
            for (int j = 0; j < FN; ++j)
                acc[i][j] = __builtin_amdgcn_mfma_f32_16x16x32_bf16(af[i], bfr[j], acc[i][j], 0, 0, 0);
        cur ^= 1;
    }

    // Epilogue. C/D layout: col=lane&15, row=(lane>>4)*4+reg (verified r6-r8).
    #pragma unroll
    for (int i = 0; i < FM; ++i) {
        const int rowb = m0 + mw + i * 16 + (lane >> 4) * 4;
        #pragma unroll
        for (int j = 0; j < FN; ++j) {
            const int col = n0 + nw + j * 16 + (lane & 15);
            f32x4 v = acc[i][j];
            #pragma unroll
            for (int r = 0; r < 4; ++r) {
                float f = v[r];
                if (CF::BIAS == 1) f += bias[rowb + r];
                if (CF::BIAS == 2) f += bias[col];
                if (CF::RELU) f = fmaxf(f, 0.f);
                v[r] = f;
            }
            if (CF::STORE == 0 || CF::STORE == 2) {
                #pragma unroll
                for (int r = 0; r < 4; ++r)
                    C[(size_t)(rowb + r) * N + col] = (typename CF::OUT_T)v[r];
            }
            if (CF::STORE == 1 || CF::STORE == 2) {
                if constexpr (sizeof(typename CF::OUT_T) == 4) {
                    *(f32x4*)&CT[(size_t)col * M + rowb] = v;
                } else {
                    bf16x4 w = { (__bf16)v[0], (__bf16)v[1], (__bf16)v[2], (__bf16)v[3] };
                    *(bf16x4*)&CT[(size_t)col * M + rowb] = w;
                }
            }
        }
    }
}

template<class CF>
__global__ __launch_bounds__(256, 2)
void gemm1(const __bf16* __restrict__ A, const __bf16* __restrict__ B,
           const float* __restrict__ bias,
           typename CF::OUT_T* __restrict__ C, typename CF::OUT_T* __restrict__ CT,
           int M, int N, int K, int ntx)
{
    __shared__ char smem[CF::SMEM];
    gemm_body<CF>(blockIdx.x, smem, A, B, bias, C, CT, M, N, K, ntx);
}

// Two independent GEMMs in one launch: blocks [0,nblk1) -> #1, rest -> #2.
template<class C1, class C2>
__global__ __launch_bounds__(256, 2)
void gemm2(int nblk1,
           const __bf16* __restrict__ A1, const __bf16* __restrict__ B1,
           const float* __restrict__ b1,
           typename C1::OUT_T* __restrict__ C1p, typename C1::OUT_T* __restrict__ CT1,
           int M1, int N1, int K1, int ntx1,
           const __bf16* __restrict__ A2, const __bf16* __restrict__ B2,
           const float* __restrict__ b2,
           typename C2::OUT_T* __restrict__ C2p, typename C2::OUT_T* __restrict__ CT2,
           int M2, int N2, int K2, int ntx2)
{
    constexpr int S = C1::SMEM > C2::SMEM ? C1::SMEM : C2::SMEM;
    __shared__ char smem[S];
    if ((int)blockIdx.x < nblk1)
        gemm_body<C1>(blockIdx.x, smem, A1, B1, b1, C1p, CT1, M1, N1, K1, ntx1);
    else
        gemm_body<C2>(blockIdx.x - nblk1, smem, A2, B2, b2, C2p, CT2, M2, N2, K2, ntx2);
}

// ---------------- helpers ----------------
__device__ __forceinline__ void tp_tile(const float* __restrict__ in,
                                        __bf16* __restrict__ outp,
                                        int R, int C, int bx, int by)
{
    __shared__ float t[32][33];
    const int tx = threadIdx.x & 31, ty = threadIdx.x >> 5;  // (32,8)
    #pragma unroll
    for (int i = ty; i < 32; i += 8)
        t[i][tx] = in[(size_t)(by + i) * C + (bx + tx)];
    __syncthreads();
    #pragma unroll
    for (int i = ty; i < 32; i += 8)
        outp[(size_t)(bx + i) * R + (by + tx)] = (__bf16)t[tx][i];
}

__device__ __forceinline__ void cast_blk(const float* __restrict__ s,
                                         __bf16* __restrict__ d, int blk)
{
    const int i = blk * 1024 + threadIdx.x * 4;
    float4 v = *(const float4*)&s[i];
    bf16x4 w = { (__bf16)v.x, (__bf16)v.y, (__bf16)v.z, (__bf16)v.w };
    *(bf16x4*)&d[i] = w;
}

__device__ __forceinline__ void softmax_row(__bf16* __restrict__ p)
{
    __shared__ float red[256];
    const int t = threadIdx.x;
    bf16x8 v = *(bf16x8*)&p[t * 8];
    float f[8];
    float m = -1e30f;
    #pragma unroll
    for (int r = 0; r < 8; ++r) { f[r] = (float)v[r]; m = fmaxf(m, f[r]); }
    red[t] = m;
    __syncthreads();
    for (int s = 128; s > 0; s >>= 1) {
        if (t < s) red[t] = fmaxf(red[t], red[t + s]);
        __syncthreads();
    }
    m = red[0];
    __syncthreads();
    float sum = 0.f;
    #pragma unroll
    for (int r = 0; r < 8; ++r) { f[r] = expf(f[r] - m); sum += f[r]; }
    red[t] = sum;
    __syncthreads();
    for (int s = 128; s > 0; s >>= 1) {
        if (t < s) red[t] += red[t + s];
        __syncthreads();
    }
    const float inv = 1.f / red[0];
    bf16x8 w;
    #pragma unroll
    for (int r = 0; r < 8; ++r) w[r] = (__bf16)(f[r] * inv);
    *(bf16x8*)&p[t * 8] = w;
}

// prep: z=0 -> transpose-cast vc,vm (x in [0,4096)); z=1 -> cast W_ak (x<2048),
// W_c (2048<=x<3072).
__global__ __launch_bounds__(256)
void prep(const float* __restrict__ vc, __bf16* __restrict__ vcT,
          const float* __restrict__ vm, __bf16* __restrict__ vmT,
          const float* __restrict__ W_ak, __bf16* __restrict__ W_akb,
          const float* __restrict__ W_c, __bf16* __restrict__ W_cb)
{
    if (blockIdx.z == 0) {
        int e = blockIdx.x;                       // [0,4096)
        const float* in  = (e < 2048) ? vc : vcT ? (e < 2048 ? vc : vm) : vm;  // (kept simple below)
        in = (e < 2048) ? vc : vm;
        __bf16* o = (e < 2048) ? vcT : vmT;
        e &= 2047;
        tp_tile(in, o, 1024, 2048, (e & 63) * 32, (e >> 6) * 32);
    } else {
        const int x = blockIdx.x;
        if (x >= 3072) return;
        if (x < 2048) cast_blk(W_ak, W_akb, x);
        else          cast_blk(W_c, W_cb, x - 2048);
    }
}

// smprep: z=0 -> row softmax of ST (x<2048); z=1 -> cast W_mad (x<1024);
// z=2 -> transpose-cast W_gcn (x<1024).
__global__ __launch_bounds__(256)
void smprep(__bf16* __restrict__ ST,
            const float* __restrict__ W_mad, __bf16* __restrict__ W_madb,
            const float* __restrict__ W_gcn, __bf16* __restrict__ W_gcnT)
{
    if (blockIdx.z == 0) {
        softmax_row(ST + (size_t)blockIdx.x * 2048);
    } else if (blockIdx.z == 1) {
        if (blockIdx.x >= 1024) return;
        cast_blk(W_mad, W_madb, blockIdx.x);
    } else {
        if (blockIdx.x >= 1024) return;
        const int e = blockIdx.x;
        tp_tile(W_gcn, W_gcnT, 1024, 1024, (e & 31) * 32, (e >> 5) * 32);
    }
}

__global__ __launch_bounds__(256)
void row_softmax_k(__bf16* __restrict__ A)
{
    softmax_row(A + (size_t)blockIdx.x * 2048);
}

extern "C" void kernel_launch(void* const* d_in, const int* in_sizes, int n_in,
                              void* d_out, int out_size, void* d_ws, size_t ws_size,
                              hipStream_t stream)
{
    const float* vc    = (const float*)d_in[0];
    const float* vm    = (const float*)d_in[1];
    const float* W_ak  = (const float*)d_in[2];
    const float* b_ak  = (const float*)d_in[3];
    const float* W_c   = (const float*)d_in[4];
    const float* b_c   = (const float*)d_in[5];
    const float* W_mad = (const float*)d_in[6];
    const float* b_mad = (const float*)d_in[7];
    const float* W_gcn = (const float*)d_in[8];
    const float* b_gcn = (const float*)d_in[9];
    float* out = (float*)d_out;

    // Arena, 32 MB. Liveness (L-numbers = launch order):
    //  [0,8):   ST (wL2, smL3, rL4)   -> P (wL6, smL7, rL8)
    //  [8,12):  vcT (wL1, rL2)        -> vma1T (wL4, rL5)
    //  [12,16): W_akb (wL1, rL2)      -> vmaT (wL5, rL6)
    //  [16,20): vmT (wL1, rL2)        -> xT (wL4, rL8)
    //  [20,22): W_cb (wL1, rL2)       -> W_madb (wL3, rL5)
    //  [22,24): W_gcnT (wL3, rL4)
    //  [24,28): vmr (wL2, rL4)
    //  [28,32): vmrT (wL2, rL4)
    char* ws = (char*)d_ws;
    const size_t MB = 1u << 20;
    __bf16* ST     = (__bf16*)(ws);
    __bf16* P      = (__bf16*)(ws);
    __bf16* vcT    = (__bf16*)(ws + 8 * MB);
    __bf16* vma1T  = (__bf16*)(ws + 8 * MB);
    __bf16* W_akb  = (__bf16*)(ws + 12 * MB);
    __bf16* vmaT   = (__bf16*)(ws + 12 * MB);
    __bf16* vmT    = (__bf16*)(ws + 16 * MB);
    __bf16* xT     = (__bf16*)(ws + 16 * MB);
    __bf16* W_cb   = (__bf16*)(ws + 20 * MB);
    __bf16* W_madb = (__bf16*)(ws + 20 * MB);
    __bf16* W_gcnT = (__bf16*)(ws + 22 * MB);
    __bf16* vmr    = (__bf16*)(ws + 24 * MB);
    __bf16* vmrT   = (__bf16*)(ws + 28 * MB);

    using G3  = GC<__bf16, 128, 128, 2, false, 0>;
    using G5  = GC<__bf16, 128, 128, 1, true,  2>;
    using G7  = GC<__bf16, 128, 128, 0, false, 0>;
    using G11 = GC<__bf16, 128, 128, 1, false, 0>;
    using G8  = GC<__bf16, 128, 64,  2, false, 0>;
    using G9  = GC<__bf16, 128, 128, 0, false, 0>;
    using G12 = GC<float,  128, 64,  0, false, 1>;

    // L1. all input casts/transposes
    prep<<<dim3(4096, 1, 2), 256, 0, stream>>>(vc, vcT, vm, vmT, W_ak, W_akb, W_c, W_cb);
    // L2. [G3 | G5]: ST = vcT*W_akb + b_ak (2048x2048 K1024, 256 blk)
    //               vmr/vmrT = relu(W_cb*vmT + b_c) (1024x2048 K1024, 128 blk)
    gemm2<G3, G5><<<384, 256, 0, stream>>>(256,
        vcT, W_akb, b_ak, ST, (__bf16*)nullptr, 2048, 2048, 1024, 16,
        W_cb, vmT, b_c, vmr, vmrT, 1024, 2048, 1024, 16);
    // L3. softmax rows of ST + cast W_mad + transpose W_gcn
    smprep<<<dim3(2048, 1, 3), 256, 0, stream>>>(ST, W_mad, W_madb, W_gcn, W_gcnT);
    // L4. [G7 | G11]: vma1T = ST*vmr (2048x1024 K2048, 128 blk)
    //                xT = W_gcnT*vmrT + b_gcn (1024x2048 K1024, 128 blk)
    gemm2<G7, G11><<<256, 256, 0, stream>>>(128,
        ST, vmr, nullptr, vma1T, (__bf16*)nullptr, 2048, 1024, 2048, 8,
        W_gcnT, vmrT, b_gcn, xT, (__bf16*)nullptr, 1024, 2048, 1024, 16);
    // L5. vmaT = vma1T*W_madb + b_mad (2048x1024 K1024, 128x64 tile, 256 blk)
    gemm1<G8><<<256, 256, 0, stream>>>(vma1T, W_madb, b_mad, vmaT, (__bf16*)nullptr,
                                       2048, 1024, 1024, 16);
    // L6. P = vmaT*vmaT^T (2048x2048 K1024, 256 blk)
    gemm1<G9><<<256, 256, 0, stream>>>(vmaT, vmaT, nullptr, P, (__bf16*)nullptr,
                                       2048, 2048, 1024, 16);
    // L7. softmax rows of P
    row_softmax_k<<<2048, 256, 0, stream>>>(P);
    // L8. out = (P*xT)^T direct fp32 (2048x1024 K2048, 128x64 tile, 256 blk)
    gemm1<G12><<<256, 256, 0, stream>>>(P, xT, nullptr, (float*)nullptr, out,
                                        2048, 1024, 2048, 16);
}

// Round 10
// 214.609 us; speedup vs baseline: 4.1894x; 1.0410x over previous
//
#include <hip/hip_runtime.h>
#include <hip/hip_bf16.h>

// CHNN=1024, K=L=2048. Inputs fp32, output fp32. bf16 MFMA GEMMs (16x16x32),
// fp32 accumulation, TN layout, dbuf LDS + async global_load_lds staging.
// Round 10: 2 blocks/CU EVERYWHERE (the r7-r9 lesson: 1 block/CU has no
// co-resident partner to hide the per-K-step vmcnt(0)+barrier drain).
// All GEMMs >=512 blocks via 128x64 / 64x64 tiles; fused pairs give L2=768.

typedef __bf16 bf16x4 __attribute__((ext_vector_type(4)));
typedef __bf16 bf16x8 __attribute__((ext_vector_type(8)));
typedef float  f32x4  __attribute__((ext_vector_type(4)));

typedef const void __attribute__((address_space(1)))* gptr_t;
typedef void       __attribute__((address_space(3)))* lptr_t;

__device__ __forceinline__ void load16_lds(const __bf16* g, __bf16* l)
{
    __builtin_amdgcn_global_load_lds((gptr_t)g, (lptr_t)l, 16, 0, 0);
}

// ---------------- GEMM config + body ----------------
template<typename OT, int TM_, int TN_, int BIAS_, bool RELU_, int STORE_>
struct GC {
    using OUT_T = OT;
    static constexpr int TM = TM_, TN = TN_, BIAS = BIAS_, STORE = STORE_;
    static constexpr bool RELU = RELU_;
    static constexpr int SMEM = 2 * (TM_ + TN_) * 32 * 2;   // dbuf, bf16
};

// C(M,N) = A(M,K)*B(N,K)^T; A,B bf16 k-contiguous; BK=32; 4 waves 2x2.
// BIAS: 0 none, 1 bias[row], 2 bias[col]. STORE: 0 C[m][n], 1 CT[n][m], 2 both.
template<class CF>
__device__ __forceinline__ void gemm_body(
    int bid, char* smem,
    const __bf16* __restrict__ A, const __bf16* __restrict__ B,
    const float* __restrict__ bias,
    typename CF::OUT_T* __restrict__ C, typename CF::OUT_T* __restrict__ CT,
    int M, int N, int K, int ntx)
{
    constexpr int TM = CF::TM, TN = CF::TN;
    constexpr int FM = TM / 32, FN = TN / 32;
    constexpr int NA = TM / 64, NB = TN / 64;
    __bf16* sA = (__bf16*)smem;                  // [2][TM*32]
    __bf16* sB = (__bf16*)smem + 2 * TM * 32;    // [2][TN*32]
    const int tid = threadIdx.x, lane = tid & 63, wv = tid >> 6;
    const int m0 = (bid / ntx) * TM, n0 = (bid % ntx) * TN;
    const int mw = (wv >> 1) * (FM * 16), nw = (wv & 1) * (FN * 16);

    f32x4 acc[FM][FN];
    #pragma unroll
    for (int i = 0; i < FM; ++i)
        #pragma unroll
        for (int j = 0; j < FN; ++j)
            acc[i][j] = (f32x4){0.f, 0.f, 0.f, 0.f};

    const __bf16* gA = A + (size_t)m0 * K;
    const __bf16* gB = B + (size_t)n0 * K;

    auto stage = [&](int k0, int buf) {
        #pragma unroll
        for (int i = 0; i < NA; ++i) {
            const int c = (wv * NA + i) * 64 + lane;   // 16B chunk id
            load16_lds(gA + (size_t)(c >> 2) * K + k0 + (c & 3) * 8,
                       &sA[buf * TM * 32 + (wv * NA + i) * 512]);
        }
        #pragma unroll
        for (int i = 0; i < NB; ++i) {
            const int c = (wv * NB + i) * 64 + lane;
            load16_lds(gB + (size_t)(c >> 2) * K + k0 + (c & 3) * 8,
                       &sB[buf * TN * 32 + (wv * NB + i) * 512]);
        }
    };

    stage(0, 0);
    int cur = 0;
    for (int k0 = 0; k0 < K; k0 += 32) {
        __syncthreads();                          // buf[cur] staged (vmcnt drain)
        if (k0 + 32 < K) stage(k0 + 32, cur ^ 1); // prefetch next
        bf16x8 af[FM], bfr[FN];
        #pragma unroll
        for (int i = 0; i < FM; ++i)
            af[i] = *(const bf16x8*)&sA[cur * TM * 32 + (mw + i * 16 + (lane & 15)) * 32 + (lane >> 4) * 8];
        #pragma unroll
        for (int j = 0; j < FN; ++j)
            bfr[j] = *(const bf16x8*)&sB[cur * TN * 32 + (nw + j * 16 + (lane & 15)) * 32 + (lane >> 4) * 8];
        #pragma unroll
        for (int i = 0; i < FM; ++i)
            #pragma unroll
            for (int j = 0; j < FN; ++j)
                acc[i][j] = __builtin_amdgcn_mfma_f32_16x16x32_bf16(af[i], bfr[j], acc[i][j], 0, 0, 0);
        cur ^= 1;
    }

    // Epilogue. C/D layout: col=lane&15, row=(lane>>4)*4+reg (verified r6-r9).
    #pragma unroll
    for (int i = 0; i < FM; ++i) {
        const int rowb = m0 + mw + i * 16 + (lane >> 4) * 4;
        #pragma unroll
        for (int j = 0; j < FN; ++j) {
            const int col = n0 + nw + j * 16 + (lane & 15);
            f32x4 v = acc[i][j];
            #pragma unroll
            for (int r = 0; r < 4; ++r) {
                float f = v[r];
                if (CF::BIAS == 1) f += bias[rowb + r];
                if (CF::BIAS == 2) f += bias[col];
                if (CF::RELU) f = fmaxf(f, 0.f);
                v[r] = f;
            }
            if (CF::STORE == 0 || CF::STORE == 2) {
                #pragma unroll
                for (int r = 0; r < 4; ++r)
                    C[(size_t)(rowb + r) * N + col] = (typename CF::OUT_T)v[r];
            }
            if (CF::STORE == 1 || CF::STORE == 2) {
                if constexpr (sizeof(typename CF::OUT_T) == 4) {
                    *(f32x4*)&CT[(size_t)col * M + rowb] = v;
                } else {
                    bf16x4 w = { (__bf16)v[0], (__bf16)v[1], (__bf16)v[2], (__bf16)v[3] };
                    *(bf16x4*)&CT[(size_t)col * M + rowb] = w;
                }
            }
        }
    }
}

template<class CF>
__global__ __launch_bounds__(256, 2)
void gemm1(const __bf16* __restrict__ A, const __bf16* __restrict__ B,
           const float* __restrict__ bias,
           typename CF::OUT_T* __restrict__ C, typename CF::OUT_T* __restrict__ CT,
           int M, int N, int K, int ntx)
{
    __shared__ char smem[CF::SMEM];
    gemm_body<CF>(blockIdx.x, smem, A, B, bias, C, CT, M, N, K, ntx);
}

// Two independent GEMMs in one launch: blocks [0,nblk1) -> #1, rest -> #2.
template<class C1, class C2>
__global__ __launch_bounds__(256, 2)
void gemm2(int nblk1,
           const __bf16* __restrict__ A1, const __bf16* __restrict__ B1,
           const float* __restrict__ b1,
           typename C1::OUT_T* __restrict__ C1p, typename C1::OUT_T* __restrict__ CT1,
           int M1, int N1, int K1, int ntx1,
           const __bf16* __restrict__ A2, const __bf16* __restrict__ B2,
           const float* __restrict__ b2,
           typename C2::OUT_T* __restrict__ C2p, typename C2::OUT_T* __restrict__ CT2,
           int M2, int N2, int K2, int ntx2)
{
    constexpr int S = C1::SMEM > C2::SMEM ? C1::SMEM : C2::SMEM;
    __shared__ char smem[S];
    if ((int)blockIdx.x < nblk1)
        gemm_body<C1>(blockIdx.x, smem, A1, B1, b1, C1p, CT1, M1, N1, K1, ntx1);
    else
        gemm_body<C2>(blockIdx.x - nblk1, smem, A2, B2, b2, C2p, CT2, M2, N2, K2, ntx2);
}

// ---------------- helpers ----------------
__device__ __forceinline__ void tp_tile(const float* __restrict__ in,
                                        __bf16* __restrict__ outp,
                                        int R, int C, int bx, int by)
{
    __shared__ float t[32][33];
    const int tx = threadIdx.x & 31, ty = threadIdx.x >> 5;  // (32,8)
    #pragma unroll
    for (int i = ty; i < 32; i += 8)
        t[i][tx] = in[(size_t)(by + i) * C + (bx + tx)];
    __syncthreads();
    #pragma unroll
    for (int i = ty; i < 32; i += 8)
        outp[(size_t)(bx + i) * R + (by + tx)] = (__bf16)t[tx][i];
}

__device__ __forceinline__ void cast_blk(const float* __restrict__ s,
                                         __bf16* __restrict__ d, int blk)
{
    const int i = blk * 1024 + threadIdx.x * 4;
    float4 v = *(const float4*)&s[i];
    bf16x4 w = { (__bf16)v.x, (__bf16)v.y, (__bf16)v.z, (__bf16)v.w };
    *(bf16x4*)&d[i] = w;
}

__device__ __forceinline__ void softmax_row(__bf16* __restrict__ p)
{
    __shared__ float red[256];
    const int t = threadIdx.x;
    bf16x8 v = *(bf16x8*)&p[t * 8];
    float f[8];
    float m = -1e30f;
    #pragma unroll
    for (int r = 0; r < 8; ++r) { f[r] = (float)v[r]; m = fmaxf(m, f[r]); }
    red[t] = m;
    __syncthreads();
    for (int s = 128; s > 0; s >>= 1) {
        if (t < s) red[t] = fmaxf(red[t], red[t + s]);
        __syncthreads();
    }
    m = red[0];
    __syncthreads();
    float sum = 0.f;
    #pragma unroll
    for (int r = 0; r < 8; ++r) { f[r] = expf(f[r] - m); sum += f[r]; }
    red[t] = sum;
    __syncthreads();
    for (int s = 128; s > 0; s >>= 1) {
        if (t < s) red[t] += red[t + s];
        __syncthreads();
    }
    const float inv = 1.f / red[0];
    bf16x8 w;
    #pragma unroll
    for (int r = 0; r < 8; ++r) w[r] = (__bf16)(f[r] * inv);
    *(bf16x8*)&p[t * 8] = w;
}

// prep: z=0 -> transpose-cast vc (x<2048) / vm (x in [2048,4096));
//       z=1 -> cast W_ak (x<2048), W_c ([2048,3072)), W_mad ([3072,4096));
//       z=2 -> transpose-cast W_gcn (x<1024).
__global__ __launch_bounds__(256)
void prep(const float* __restrict__ vc, __bf16* __restrict__ vcT,
          const float* __restrict__ vm, __bf16* __restrict__ vmT,
          const float* __restrict__ W_ak, __bf16* __restrict__ W_akb,
          const float* __restrict__ W_c, __bf16* __restrict__ W_cb,
          const float* __restrict__ W_mad, __bf16* __restrict__ W_madb,
          const float* __restrict__ W_gcn, __bf16* __restrict__ W_gcnT)
{
    const int x = blockIdx.x;
    if (blockIdx.z == 0) {
        const float* in = (x < 2048) ? vc : vm;
        __bf16* o       = (x < 2048) ? vcT : vmT;
        const int e = x & 2047;
        tp_tile(in, o, 1024, 2048, (e & 63) * 32, (e >> 6) * 32);
    } else if (blockIdx.z == 1) {
        if (x < 2048)      cast_blk(W_ak, W_akb, x);
        else if (x < 3072) cast_blk(W_c, W_cb, x - 2048);
        else               cast_blk(W_mad, W_madb, x - 3072);
    } else {
        if (x >= 1024) return;
        tp_tile(W_gcn, W_gcnT, 1024, 1024, (x & 31) * 32, (x >> 5) * 32);
    }
}

__global__ __launch_bounds__(256)
void row_softmax_k(__bf16* __restrict__ A)
{
    softmax_row(A + (size_t)blockIdx.x * 2048);
}

extern "C" void kernel_launch(void* const* d_in, const int* in_sizes, int n_in,
                              void* d_out, int out_size, void* d_ws, size_t ws_size,
                              hipStream_t stream)
{
    const float* vc    = (const float*)d_in[0];
    const float* vm    = (const float*)d_in[1];
    const float* W_ak  = (const float*)d_in[2];
    const float* b_ak  = (const float*)d_in[3];
    const float* W_c   = (const float*)d_in[4];
    const float* b_c   = (const float*)d_in[5];
    const float* W_mad = (const float*)d_in[6];
    const float* b_mad = (const float*)d_in[7];
    const float* W_gcn = (const float*)d_in[8];
    const float* b_gcn = (const float*)d_in[9];
    float* out = (float*)d_out;

    // Arena, 32 MB. Liveness (L-numbers = launch order):
    //  [0,8):   ST (wL2, smL3, rL4)   -> P (wL6, smL7, rL8)
    //  [8,12):  vcT (wL1, rL2)        -> vma1T (wL4, rL5)
    //  [12,16): W_akb (wL1, rL2)      -> vmaT (wL5, rL6)
    //  [16,20): vmT (wL1, rL2)        -> xT (wL4, rL8)
    //  [20,22): W_cb (wL1, rL2)       -> W_madb (wL1, rL5)  [written once, L1]
    //  [22,24): W_gcnT (wL1, rL4)
    //  [24,28): vmr (wL2, rL4)
    //  [28,32): vmrT (wL2, rL4)
    // NOTE: W_cb region is read by L2 and W_madb written in L1 -- give W_madb
    // its own bytes instead: W_cb [20,22), W_madb [30,32)? vmrT is [28,32).
    // Keep it simple: W_cb [20,21)? W_c is 2 MB bf16. Layout below uses
    // separate slots: W_cb [20,22), W_madb [22,24), W_gcnT [24,26),
    // vmr [26,30) -> overlaps? Recomputed cleanly:
    //  [0,8):   ST -> P
    //  [8,12):  vcT -> vma1T
    //  [12,16): W_akb -> vmaT
    //  [16,20): vmT -> xT
    //  [20,22): W_cb (rL2 dead after) ; [22,24): W_madb ; [24,26): W_gcnT
    //  [26,28): (unused)
    //  [28,30)+[30,32): vmr needs 4MB -> [28,32); vmrT needs 4MB -> conflict.
    // Final: vmr [26,30), vmrT: reuse W_cb+pad? Use exact map in code below
    // (36 MB would overflow) -- vmrT goes to [30,32)+? Not enough. Solution:
    // W_cb dead after L2; vmrT written in L2 epilogue (same launch!) -> cannot
    // overlap W_cb. vmrT -> [4,8) half of ST? ST live. Use: vmrT [12,16)?
    // W_akb read in L2 same launch. -> keep r9's proven map (W_madb shared
    // write L1 / no conflict since W_cb read and W_madb write are in
    // DIFFERENT 1MB-granular slots): W_cb [20,22), W_madb [22,24),
    // W_gcnT [24,26), vmr [26,30)... vmrT needs [30,34) > 32 MB. Revert to
    // r9 trick: W_madb at [20,22) shares W_cb's slot but is written in L1
    // while W_cb is still needed in L2 -> BROKEN in r9?? No: r9 wrote W_madb
    // in L3 (after L2). Here keep W_mad cast in a z=1 tail but W_madb slot
    // [22,24): fine, no sharing. vmrT: reuse ST's second half? ST is 8 MB
    // live until L4; vmrT read in L4. -> Allocate vmrT at [4,8) is illegal.
    // FINAL clean map (fits 32 MB): see code.
    char* ws = (char*)d_ws;
    const size_t MB = 1u << 20;
    __bf16* ST     = (__bf16*)(ws);            // [0,8)    -> P
    __bf16* P      = (__bf16*)(ws);
    __bf16* vcT    = (__bf16*)(ws + 8 * MB);   // [8,12)   -> vma1T
    __bf16* vma1T  = (__bf16*)(ws + 8 * MB);
    __bf16* W_akb  = (__bf16*)(ws + 12 * MB);  // [12,16)  -> vmaT
    __bf16* vmaT   = (__bf16*)(ws + 12 * MB);
    __bf16* vmT    = (__bf16*)(ws + 16 * MB);  // [16,20)  -> xT
    __bf16* xT     = (__bf16*)(ws + 16 * MB);
    __bf16* W_cb   = (__bf16*)(ws + 20 * MB);  // [20,22)
    __bf16* W_madb = (__bf16*)(ws + 22 * MB);  // [22,24)
    __bf16* vmr    = (__bf16*)(ws + 24 * MB);  // [24,28)
    __bf16* vmrT   = (__bf16*)(ws + 28 * MB);  // [28,32)
    __bf16* W_gcnT = (__bf16*)(ws + 20 * MB);  // reuse W_cb slot? W_cb read L2,
    // W_gcnT written L1 -> conflict! Put W_gcnT in its own spare: [22,24) is
    // W_madb (read L5). No spare left... use d_out as scratch? out_size =
    // 2048*1024 fp32 = 8 MB, written only in L8. W_gcnT (2 MB) -> d_out!
    W_gcnT = (__bf16*)((char*)d_out + 0);      // d_out scratch until L8? L8
    // WRITES out while READING xT (not W_gcnT -- W_gcnT dead after L4). Safe:
    // d_out poisoned pre-launch, we own it; W_gcnT read last in L4, out
    // written in L8. No overlap.

    using G3  = GC<__bf16, 128, 64, 2, false, 0>;   // 512 blk
    using G5  = GC<__bf16, 128, 64, 1, true,  2>;   // 256 blk
    using G7  = GC<__bf16, 128, 64, 0, false, 0>;   // 256 blk
    using G11 = GC<__bf16, 128, 64, 1, false, 0>;   // 256 blk
    using G8  = GC<__bf16, 64,  64, 2, false, 0>;   // 512 blk
    using G9  = GC<__bf16, 128, 64, 0, false, 0>;   // 512 blk
    using G12 = GC<float,  64,  64, 0, false, 1>;   // 512 blk

    // L1. all input casts/transposes
    prep<<<dim3(4096, 1, 3), 256, 0, stream>>>(vc, vcT, vm, vmT, W_ak, W_akb,
                                               W_c, W_cb, W_mad, W_madb,
                                               W_gcn, W_gcnT);
    // L2. [G3|G5] 768 blk (3/CU): ST = vcT*W_akb + b_ak (2048x2048 K1024)
    //                             vmr/vmrT = relu(W_cb*vmT + b_c) (1024x2048 K1024)
    gemm2<G3, G5><<<768, 256, 0, stream>>>(512,
        vcT, W_akb, b_ak, ST, (__bf16*)nullptr, 2048, 2048, 1024, 32,
        W_cb, vmT, b_c, vmr, vmrT, 1024, 2048, 1024, 32);
    // L3. softmax rows of ST
    row_softmax_k<<<2048, 256, 0, stream>>>(ST);
    // L4. [G7|G11] 512 blk (2/CU): vma1T = ST*vmr (2048x1024 K2048)
    //                              xT = W_gcnT*vmrT + b_gcn (1024x2048 K1024)
    gemm2<G7, G11><<<512, 256, 0, stream>>>(256,
        ST, vmr, nullptr, vma1T, (__bf16*)nullptr, 2048, 1024, 2048, 16,
        W_gcnT, vmrT, b_gcn, xT, (__bf16*)nullptr, 1024, 2048, 1024, 32);
    // L5. G8 512 blk: vmaT = vma1T*W_madb + b_mad (2048x1024 K1024)
    gemm1<G8><<<512, 256, 0, stream>>>(vma1T, W_madb, b_mad, vmaT, (__bf16*)nullptr,
                                       2048, 1024, 1024, 16);
    // L6. G9 512 blk: P = vmaT*vmaT^T (2048x2048 K1024)
    gemm1<G9><<<512, 256, 0, stream>>>(vmaT, vmaT, nullptr, P, (__bf16*)nullptr,
                                       2048, 2048, 1024, 32);
    // L7. softmax rows of P
    row_softmax_k<<<2048, 256, 0, stream>>>(P);
    // L8. G12 512 blk: out = (P*xT)^T direct fp32 (2048x1024 K2048)
    gemm1<G12><<<512, 256, 0, stream>>>(P, xT, nullptr, (float*)nullptr, out,
                                        2048, 1024, 2048, 16);
}

// Round 11
// 211.267 us; speedup vs baseline: 4.2557x; 1.0158x over previous
//
#include <hip/hip_runtime.h>
#include <hip/hip_bf16.h>

// CHNN=1024, K=L=2048. Inputs fp32, output fp32. bf16 MFMA GEMMs (16x16x32),
// fp32 acc, TN layout, dbuf LDS + async global_load_lds staging, >=512 blk/GEMM.
// Round 11: critical-path surgery via associativity:
//   vma = W_mad@(vmr@w) + b  ==  (W_mad@vmr)@w + b
// so vmm = W_mad@vmr computes in the softmax's launch slot (off-chain), and
// the old serial G8 stage disappears. 7 launches; chain = 34.4 GF (was 38.6).

typedef __bf16 bf16x4 __attribute__((ext_vector_type(4)));
typedef __bf16 bf16x8 __attribute__((ext_vector_type(8)));
typedef float  f32x4  __attribute__((ext_vector_type(4)));

typedef const void __attribute__((address_space(1)))* gptr_t;
typedef void       __attribute__((address_space(3)))* lptr_t;

__device__ __forceinline__ void load16_lds(const __bf16* g, __bf16* l)
{
    __builtin_amdgcn_global_load_lds((gptr_t)g, (lptr_t)l, 16, 0, 0);
}

// ---------------- GEMM config + body ----------------
template<typename OT, int TM_, int TN_, int BIAS_, bool RELU_, int STORE_>
struct GC {
    using OUT_T = OT;
    static constexpr int TM = TM_, TN = TN_, BIAS = BIAS_, STORE = STORE_;
    static constexpr bool RELU = RELU_;
    static constexpr int SMEM = 2 * (TM_ + TN_) * 32 * 2;   // dbuf, bf16
};

// C(M,N) = A(M,K)*B(N,K)^T; A,B bf16 k-contiguous; BK=32; 4 waves 2x2.
// BIAS: 0 none, 1 bias[row], 2 bias[col]. STORE: 0 C[m][n], 1 CT[n][m], 2 both.
template<class CF>
__device__ __forceinline__ void gemm_body(
    int bid, char* smem,
    const __bf16* __restrict__ A, const __bf16* __restrict__ B,
    const float* __restrict__ bias,
    typename CF::OUT_T* __restrict__ C, typename CF::OUT_T* __restrict__ CT,
    int M, int N, int K, int ntx)
{
    constexpr int TM = CF::TM, TN = CF::TN;
    constexpr int FM = TM / 32, FN = TN / 32;
    constexpr int NA = TM / 64, NB = TN / 64;
    __bf16* sA = (__bf16*)smem;                  // [2][TM*32]
    __bf16* sB = (__bf16*)smem + 2 * TM * 32;    // [2][TN*32]
    const int tid = threadIdx.x, lane = tid & 63, wv = tid >> 6;
    const int m0 = (bid / ntx) * TM, n0 = (bid % ntx) * TN;
    const int mw = (wv >> 1) * (FM * 16), nw = (wv & 1) * (FN * 16);

    f32x4 acc[FM][FN];
    #pragma unroll
    for (int i = 0; i < FM; ++i)
        #pragma unroll
        for (int j = 0; j < FN; ++j)
            acc[i][j] = (f32x4){0.f, 0.f, 0.f, 0.f};

    const __bf16* gA = A + (size_t)m0 * K;
    const __bf16* gB = B + (size_t)n0 * K;

    auto stage = [&](int k0, int buf) {
        #pragma unroll
        for (int i = 0; i < NA; ++i) {
            const int c = (wv * NA + i) * 64 + lane;   // 16B chunk id
            load16_lds(gA + (size_t)(c >> 2) * K + k0 + (c & 3) * 8,
                       &sA[buf * TM * 32 + (wv * NA + i) * 512]);
        }
        #pragma unroll
        for (int i = 0; i < NB; ++i) {
            const int c = (wv * NB + i) * 64 + lane;
            load16_lds(gB + (size_t)(c >> 2) * K + k0 + (c & 3) * 8,
                       &sB[buf * TN * 32 + (wv * NB + i) * 512]);
        }
    };

    stage(0, 0);
    int cur = 0;
    for (int k0 = 0; k0 < K; k0 += 32) {
        __syncthreads();                          // buf[cur] staged (vmcnt drain)
        if (k0 + 32 < K) stage(k0 + 32, cur ^ 1); // prefetch next
        bf16x8 af[FM], bfr[FN];
        #pragma unroll
        for (int i = 0; i < FM; ++i)
            af[i] = *(const bf16x8*)&sA[cur * TM * 32 + (mw + i * 16 + (lane & 15)) * 32 + (lane >> 4) * 8];
        #pragma unroll
        for (int j = 0; j < FN; ++j)
            bfr[j] = *(const bf16x8*)&sB[cur * TN * 32 + (nw + j * 16 + (lane & 15)) * 32 + (lane >> 4) * 8];
        #pragma unroll
        for (int i = 0; i < FM; ++i)
            #pragma unroll
            for (int j = 0; j < FN; ++j)
                acc[i][j] = __builtin_amdgcn_mfma_f32_16x16x32_bf16(af[i], bfr[j], acc[i][j], 0, 0, 0);
        cur ^= 1;
    }

    // Epilogue. C/D layout: col=lane&15, row=(lane>>4)*4+reg (verified r6-r10).
    #pragma unroll
    for (int i = 0; i < FM; ++i) {
        const int rowb = m0 + mw + i * 16 + (lane >> 4) * 4;
        #pragma unroll
        for (int j = 0; j < FN; ++j) {
            const int col = n0 + nw + j * 16 + (lane & 15);
            f32x4 v = acc[i][j];
            #pragma unroll
            for (int r = 0; r < 4; ++r) {
                float f = v[r];
                if (CF::BIAS == 1) f += bias[rowb + r];
                if (CF::BIAS == 2) f += bias[col];
                if (CF::RELU) f = fmaxf(f, 0.f);
                v[r] = f;
            }
            if (CF::STORE == 0 || CF::STORE == 2) {
                #pragma unroll
                for (int r = 0; r < 4; ++r)
                    C[(size_t)(rowb + r) * N + col] = (typename CF::OUT_T)v[r];
            }
            if (CF::STORE == 1 || CF::STORE == 2) {
                if constexpr (sizeof(typename CF::OUT_T) == 4) {
                    *(f32x4*)&CT[(size_t)col * M + rowb] = v;
                } else {
                    bf16x4 w = { (__bf16)v[0], (__bf16)v[1], (__bf16)v[2], (__bf16)v[3] };
                    *(bf16x4*)&CT[(size_t)col * M + rowb] = w;
                }
            }
        }
    }
}

template<class CF>
__global__ __launch_bounds__(256, 2)
void gemm1(const __bf16* __restrict__ A, const __bf16* __restrict__ B,
           const float* __restrict__ bias,
           typename CF::OUT_T* __restrict__ C, typename CF::OUT_T* __restrict__ CT,
           int M, int N, int K, int ntx)
{
    __shared__ char smem[CF::SMEM];
    gemm_body<CF>(blockIdx.x, smem, A, B, bias, C, CT, M, N, K, ntx);
}

// Two independent GEMMs in one launch.
template<class C1, class C2>
__global__ __launch_bounds__(256, 2)
void gemm2(int nblk1,
           const __bf16* __restrict__ A1, const __bf16* __restrict__ B1,
           const float* __restrict__ b1,
           typename C1::OUT_T* __restrict__ C1p, typename C1::OUT_T* __restrict__ CT1,
           int M1, int N1, int K1, int ntx1,
           const __bf16* __restrict__ A2, const __bf16* __restrict__ B2,
           const float* __restrict__ b2,
           typename C2::OUT_T* __restrict__ C2p, typename C2::OUT_T* __restrict__ CT2,
           int M2, int N2, int K2, int ntx2)
{
    constexpr int S = C1::SMEM > C2::SMEM ? C1::SMEM : C2::SMEM;
    __shared__ char smem[S];
    if ((int)blockIdx.x < nblk1)
        gemm_body<C1>(blockIdx.x, smem, A1, B1, b1, C1p, CT1, M1, N1, K1, ntx1);
    else
        gemm_body<C2>(blockIdx.x - nblk1, smem, A2, B2, b2, C2p, CT2, M2, N2, K2, ntx2);
}

__device__ __forceinline__ void softmax_row(__bf16* __restrict__ p)
{
    __shared__ float red[256];
    const int t = threadIdx.x;
    bf16x8 v = *(bf16x8*)&p[t * 8];
    float f[8];
    float m = -1e30f;
    #pragma unroll
    for (int r = 0; r < 8; ++r) { f[r] = (float)v[r]; m = fmaxf(m, f[r]); }
    red[t] = m;
    __syncthreads();
    for (int s = 128; s > 0; s >>= 1) {
        if (t < s) red[t] = fmaxf(red[t], red[t + s]);
        __syncthreads();
    }
    m = red[0];
    __syncthreads();
    float sum = 0.f;
    #pragma unroll
    for (int r = 0; r < 8; ++r) { f[r] = expf(f[r] - m); sum += f[r]; }
    red[t] = sum;
    __syncthreads();
    for (int s = 128; s > 0; s >>= 1) {
        if (t < s) red[t] += red[t + s];
        __syncthreads();
    }
    const float inv = 1.f / red[0];
    bf16x8 w;
    #pragma unroll
    for (int r = 0; r < 8; ++r) w[r] = (__bf16)(f[r] * inv);
    *(bf16x8*)&p[t * 8] = w;
}

// Two independent GEMMs + row-softmax batch in one launch.
template<class C1, class C2>
__global__ __launch_bounds__(256, 2)
void gemm2sm(int nblk1, int nblk2,
             const __bf16* __restrict__ A1, const __bf16* __restrict__ B1,
             const float* __restrict__ b1,
             typename C1::OUT_T* __restrict__ C1p,
             int M1, int N1, int K1, int ntx1,
             const __bf16* __restrict__ A2, const __bf16* __restrict__ B2,
             const float* __restrict__ b2,
             typename C2::OUT_T* __restrict__ C2p,
             int M2, int N2, int K2, int ntx2,
             __bf16* __restrict__ SM)
{
    constexpr int S = C1::SMEM > C2::SMEM ? C1::SMEM : C2::SMEM;
    __shared__ char smem[S];
    const int b = blockIdx.x;
    if (b < nblk1)
        gemm_body<C1>(b, smem, A1, B1, b1, C1p, (typename C1::OUT_T*)nullptr,
                      M1, N1, K1, ntx1);
    else if (b < nblk1 + nblk2)
        gemm_body<C2>(b - nblk1, smem, A2, B2, b2, C2p, (typename C2::OUT_T*)nullptr,
                      M2, N2, K2, ntx2);
    else
        softmax_row(SM + (size_t)(b - nblk1 - nblk2) * 2048);
}

// ---------------- helpers ----------------
__device__ __forceinline__ void tp_tile(const float* __restrict__ in,
                                        __bf16* __restrict__ outp,
                                        int R, int C, int bx, int by)
{
    __shared__ float t[32][33];
    const int tx = threadIdx.x & 31, ty = threadIdx.x >> 5;  // (32,8)
    #pragma unroll
    for (int i = ty; i < 32; i += 8)
        t[i][tx] = in[(size_t)(by + i) * C + (bx + tx)];
    __syncthreads();
    #pragma unroll
    for (int i = ty; i < 32; i += 8)
        outp[(size_t)(bx + i) * R + (by + tx)] = (__bf16)t[tx][i];
}

__device__ __forceinline__ void cast_blk(const float* __restrict__ s,
                                         __bf16* __restrict__ d, int blk)
{
    const int i = blk * 1024 + threadIdx.x * 4;
    float4 v = *(const float4*)&s[i];
    bf16x4 w = { (__bf16)v.x, (__bf16)v.y, (__bf16)v.z, (__bf16)v.w };
    *(bf16x4*)&d[i] = w;
}

// prep: z=0 -> transpose-cast vc (x<2048) / vm ([2048,4096));
//       z=1 -> cast W_ak (x<2048), W_c ([2048,3072)), W_mad ([3072,4096));
//       z=2 -> transpose-cast W_gcn (x<1024).
__global__ __launch_bounds__(256)
void prep(const float* __restrict__ vc, __bf16* __restrict__ vcT,
          const float* __restrict__ vm, __bf16* __restrict__ vmT,
          const float* __restrict__ W_ak, __bf16* __restrict__ W_akb,
          const float* __restrict__ W_c, __bf16* __restrict__ W_cb,
          const float* __restrict__ W_mad, __bf16* __restrict__ W_madb,
          const float* __restrict__ W_gcn, __bf16* __restrict__ W_gcnT)
{
    const int x = blockIdx.x;
    if (blockIdx.z == 0) {
        const float* in = (x < 2048) ? vc : vm;
        __bf16* o       = (x < 2048) ? vcT : vmT;
        const int e = x & 2047;
        tp_tile(in, o, 1024, 2048, (e & 63) * 32, (e >> 6) * 32);
    } else if (blockIdx.z == 1) {
        if (x < 2048)      cast_blk(W_ak, W_akb, x);
        else if (x < 3072) cast_blk(W_c, W_cb, x - 2048);
        else               cast_blk(W_mad, W_madb, x - 3072);
    } else {
        if (x >= 1024) return;
        tp_tile(W_gcn, W_gcnT, 1024, 1024, (x & 31) * 32, (x >> 5) * 32);
    }
}

__global__ __launch_bounds__(256)
void row_softmax_k(__bf16* __restrict__ A)
{
    softmax_row(A + (size_t)blockIdx.x * 2048);
}

extern "C" void kernel_launch(void* const* d_in, const int* in_sizes, int n_in,
                              void* d_out, int out_size, void* d_ws, size_t ws_size,
                              hipStream_t stream)
{
    const float* vc    = (const float*)d_in[0];
    const float* vm    = (const float*)d_in[1];
    const float* W_ak  = (const float*)d_in[2];
    const float* b_ak  = (const float*)d_in[3];
    const float* W_c   = (const float*)d_in[4];
    const float* b_c   = (const float*)d_in[5];
    const float* W_mad = (const float*)d_in[6];
    const float* b_mad = (const float*)d_in[7];
    const float* W_gcn = (const float*)d_in[8];
    const float* b_gcn = (const float*)d_in[9];
    float* out = (float*)d_out;

    // Arena, 32 MB. Liveness (L = launch order below):
    //  [0,8):   ST (wL2, smL3, rL4)  -> P (wL5, smL6, rL7)
    //  [8,12):  vcT (wL1, rL2)       -> vmaT (wL4, rL5)
    //  [12,16): W_akb (wL1, rL2)     -> vmm (wL3, rL4)
    //  [16,20): vmT (wL1, rL2)       -> xT (wL3, rL7)
    //  [20,22): W_cb (wL1, rL2)
    //  [22,24): W_madb (wL1, rL3)
    //  [24,28): vmrT (wL2, rL3)
    //  [28,30): W_gcnT (wL1, rL3)
    char* ws = (char*)d_ws;
    const size_t MB = 1u << 20;
    __bf16* ST     = (__bf16*)(ws);
    __bf16* P      = (__bf16*)(ws);
    __bf16* vcT    = (__bf16*)(ws + 8 * MB);
    __bf16* vmaT   = (__bf16*)(ws + 8 * MB);
    __bf16* W_akb  = (__bf16*)(ws + 12 * MB);
    __bf16* vmm    = (__bf16*)(ws + 12 * MB);
    __bf16* vmT    = (__bf16*)(ws + 16 * MB);
    __bf16* xT     = (__bf16*)(ws + 16 * MB);
    __bf16* W_cb   = (__bf16*)(ws + 20 * MB);
    __bf16* W_madb = (__bf16*)(ws + 22 * MB);
    __bf16* vmrT   = (__bf16*)(ws + 24 * MB);
    __bf16* W_gcnT = (__bf16*)(ws + 28 * MB);

    using G3  = GC<__bf16, 128, 64, 2, false, 0>;   // ST: 512 blk
    using G5  = GC<__bf16, 128, 64, 1, true,  1>;   // vmrT only: 256 blk
    using G6  = GC<__bf16, 128, 64, 0, false, 0>;   // vmm = W_madb*vmrT: 256 blk
    using G11 = GC<__bf16, 128, 64, 1, false, 0>;   // xT: 256 blk
    using G7  = GC<__bf16, 64,  64, 2, false, 0>;   // vmaT = ST*vmm + b_mad: 512 blk
    using G9  = GC<__bf16, 128, 64, 0, false, 0>;   // P: 512 blk
    using G12 = GC<float,  64,  64, 0, false, 1>;   // out: 512 blk

    // L1. all input casts/transposes
    prep<<<dim3(4096, 1, 3), 256, 0, stream>>>(vc, vcT, vm, vmT, W_ak, W_akb,
                                               W_c, W_cb, W_mad, W_madb,
                                               W_gcn, W_gcnT);
    // L2. [G3|G5] 768 blk: ST = vcT*W_akb + b_ak (2048x2048 K1024)
    //                      vmrT = relu(W_cb*vmT + b_c)^T (1024x2048 K1024)
    gemm2<G3, G5><<<768, 256, 0, stream>>>(512,
        vcT, W_akb, b_ak, ST, (__bf16*)nullptr, 2048, 2048, 1024, 32,
        W_cb, vmT, b_c, (__bf16*)nullptr, vmrT, 1024, 2048, 1024, 32);
    // L3. [G6|G11|sm] 2560 blk: vmm = W_madb*vmrT (1024x2048 K1024)
    //                           xT = W_gcnT*vmrT + b_gcn (1024x2048 K1024)
    //                           row-softmax of ST (2048 rows)
    gemm2sm<G6, G11><<<2560, 256, 0, stream>>>(256, 256,
        W_madb, vmrT, nullptr, vmm, 1024, 2048, 1024, 32,
        W_gcnT, vmrT, b_gcn, xT, 1024, 2048, 1024, 32,
        ST);
    // L4. G7 512 blk: vmaT = ST_sm*vmm + b_mad (2048x1024 K2048)
    gemm1<G7><<<512, 256, 0, stream>>>(ST, vmm, b_mad, vmaT, (__bf16*)nullptr,
                                       2048, 1024, 2048, 16);
    // L5. G9 512 blk: P = vmaT*vmaT^T (2048x2048 K1024)
    gemm1<G9><<<512, 256, 0, stream>>>(vmaT, vmaT, nullptr, P, (__bf16*)nullptr,
                                       2048, 2048, 1024, 32);
    // L6. softmax rows of P
    row_softmax_k<<<2048, 256, 0, stream>>>(P);
    // L7. G12 512 blk: out = (P*xT)^T direct fp32 (2048x1024 K2048)
    gemm1<G12><<<512, 256, 0, stream>>>(P, xT, nullptr, (float*)nullptr, out,
                                        2048, 1024, 2048, 16);
}

// Round 12
// 208.206 us; speedup vs baseline: 4.3183x; 1.0147x over previous
//
#include <hip/hip_runtime.h>
#include <hip/hip_bf16.h>

// CHNN=1024, K=L=2048. Inputs fp32, output fp32. bf16 MFMA (16x16x32), fp32
// acc, TN layout. Round 12: BARRIER-FREE single-wave GEMM blocks (64 threads,
// 64x64 tile, 16 MFMA + 8 ds_read_b128 per K-step). No __syncthreads ->
// no compiler vmcnt(0) drain; manual s_waitcnt vmcnt(8) pipelining with
// 2-tile-deep global_load_lds prefetch (in-order vmcnt retirement).
// Same dataflow as r11: 7 launches, vmm-associativity trick, fused launches.

typedef __bf16 bf16x4 __attribute__((ext_vector_type(4)));
typedef __bf16 bf16x8 __attribute__((ext_vector_type(8)));
typedef float  f32x4  __attribute__((ext_vector_type(4)));

typedef const void __attribute__((address_space(1)))* gptr_t;
typedef void       __attribute__((address_space(3)))* lptr_t;

__device__ __forceinline__ void load16_lds(const __bf16* g, __bf16* l)
{
    __builtin_amdgcn_global_load_lds((gptr_t)g, (lptr_t)l, 16, 0, 0);
}

// s_waitcnt imm (gfx9 encoding): vmcnt[3:0]|[15:14], expcnt[6:4], lgkmcnt[11:8]
#define WAITCNT_VM8 0x0F78   // vmcnt(8), no exp/lgkm wait
#define WAITCNT_VM0 0x0F70   // vmcnt(0), no exp/lgkm wait

template<typename OT, int BIAS_, bool RELU_, int STORE_>
struct GC {
    using OUT_T = OT;
    static constexpr int BIAS = BIAS_, STORE = STORE_;
    static constexpr bool RELU = RELU_;
};

// Single-wave 64x64 TN GEMM body. C(M,N) = A(M,K)*B(N,K)^T (+bias, relu).
// sA/sB: 2 x 4KB LDS buffers each. BIAS: 0 none,1 row,2 col.
// STORE: 0 C[m][n], 1 CT[n][m] (16B vec over m).
template<class CF>
__device__ __forceinline__ void gemm_body(
    int bid, __bf16* sA, __bf16* sB,
    const __bf16* __restrict__ A, const __bf16* __restrict__ B,
    const float* __restrict__ bias,
    typename CF::OUT_T* __restrict__ C, typename CF::OUT_T* __restrict__ CT,
    int M, int N, int K, int ntx)
{
    const int lane = threadIdx.x & 63;
    const int m0 = (bid / ntx) * 64, n0 = (bid % ntx) * 64;
    const __bf16* gA = A + (size_t)m0 * K;
    const __bf16* gB = B + (size_t)n0 * K;

    f32x4 acc[4][4];
    #pragma unroll
    for (int i = 0; i < 4; ++i)
        #pragma unroll
        for (int j = 0; j < 4; ++j)
            acc[i][j] = (f32x4){0.f, 0.f, 0.f, 0.f};

    // stage one 64x32 bf16 tile pair (4KB+4KB): chunk c=i*64+lane -> row c>>2,
    // k-offset (c&3)*8; LDS dest = wave-uniform base + lane*16 (instr i -> +i*512).
    auto stage = [&](int k0, int buf) {
        #pragma unroll
        for (int i = 0; i < 4; ++i) {
            const int c = i * 64 + lane;
            load16_lds(gA + (size_t)(c >> 2) * K + k0 + (c & 3) * 8,
                       &sA[buf * 2048 + i * 512]);
        }
        #pragma unroll
        for (int i = 0; i < 4; ++i) {
            const int c = i * 64 + lane;
            load16_lds(gB + (size_t)(c >> 2) * K + k0 + (c & 3) * 8,
                       &sB[buf * 2048 + i * 512]);
        }
    };

    stage(0, 0);
    stage(32, 1);
    int cur = 0;
    for (int k0 = 0; k0 < K - 32; k0 += 32) {
        __builtin_amdgcn_s_waitcnt(WAITCNT_VM8);   // cur's 8 loads retired
        bf16x8 af[4], bfr[4];
        #pragma unroll
        for (int i = 0; i < 4; ++i) {
            af[i]  = *(const bf16x8*)&sA[cur * 2048 + (i * 16 + (lane & 15)) * 32 + (lane >> 4) * 8];
            bfr[i] = *(const bf16x8*)&sB[cur * 2048 + (i * 16 + (lane & 15)) * 32 + (lane >> 4) * 8];
        }
        #pragma unroll
        for (int i = 0; i < 4; ++i)
            #pragma unroll
            for (int j = 0; j < 4; ++j)
                acc[i][j] = __builtin_amdgcn_mfma_f32_16x16x32_bf16(af[i], bfr[j], acc[i][j], 0, 0, 0);
        if (k0 + 64 < K) stage(k0 + 64, cur);      // refill after frags consumed
        cur ^= 1;
    }
    // peeled last iteration: drain everything
    __builtin_amdgcn_s_waitcnt(WAITCNT_VM0);
    {
        bf16x8 af[4], bfr[4];
        #pragma unroll
        for (int i = 0; i < 4; ++i) {
            af[i]  = *(const bf16x8*)&sA[cur * 2048 + (i * 16 + (lane & 15)) * 32 + (lane >> 4) * 8];
            bfr[i] = *(const bf16x8*)&sB[cur * 2048 + (i * 16 + (lane & 15)) * 32 + (lane >> 4) * 8];
        }
        #pragma unroll
        for (int i = 0; i < 4; ++i)
            #pragma unroll
            for (int j = 0; j < 4; ++j)
                acc[i][j] = __builtin_amdgcn_mfma_f32_16x16x32_bf16(af[i], bfr[j], acc[i][j], 0, 0, 0);
    }

    // Epilogue. C/D layout: col=lane&15, row=(lane>>4)*4+reg (verified r6-r11).
    #pragma unroll
    for (int i = 0; i < 4; ++i) {
        const int rowb = m0 + i * 16 + (lane >> 4) * 4;
        #pragma unroll
        for (int j = 0; j < 4; ++j) {
            const int col = n0 + j * 16 + (lane & 15);
            f32x4 v = acc[i][j];
            #pragma unroll
            for (int r = 0; r < 4; ++r) {
                float f = v[r];
                if (CF::BIAS == 1) f += bias[rowb + r];
                if (CF::BIAS == 2) f += bias[col];
                if (CF::RELU) f = fmaxf(f, 0.f);
                v[r] = f;
            }
            if (CF::STORE == 0) {
                #pragma unroll
                for (int r = 0; r < 4; ++r)
                    C[(size_t)(rowb + r) * N + col] = (typename CF::OUT_T)v[r];
            } else {
                if constexpr (sizeof(typename CF::OUT_T) == 4) {
                    *(f32x4*)&CT[(size_t)col * M + rowb] = v;
                } else {
                    bf16x4 w = { (__bf16)v[0], (__bf16)v[1], (__bf16)v[2], (__bf16)v[3] };
                    *(bf16x4*)&CT[(size_t)col * M + rowb] = w;
                }
            }
        }
    }
}

// Single-wave row softmax over 2048 bf16 (32 elems/lane, shuffle reduce).
__device__ __forceinline__ void softmax_row_w(__bf16* __restrict__ p)
{
    const int lane = threadIdx.x & 63;
    bf16x8 v[4];
    float f[32];
    #pragma unroll
    for (int r = 0; r < 4; ++r)
        v[r] = *(const bf16x8*)&p[(r * 64 + lane) * 8];
    float m = -1e30f;
    #pragma unroll
    for (int r = 0; r < 4; ++r)
        #pragma unroll
        for (int j = 0; j < 8; ++j) {
            f[r * 8 + j] = (float)v[r][j];
            m = fmaxf(m, f[r * 8 + j]);
        }
    #pragma unroll
    for (int s = 1; s < 64; s <<= 1) m = fmaxf(m, __shfl_xor(m, s, 64));
    float sum = 0.f;
    #pragma unroll
    for (int i = 0; i < 32; ++i) { f[i] = expf(f[i] - m); sum += f[i]; }
    #pragma unroll
    for (int s = 1; s < 64; s <<= 1) sum += __shfl_xor(sum, s, 64);
    const float inv = 1.f / sum;
    #pragma unroll
    for (int r = 0; r < 4; ++r) {
        bf16x8 w;
        #pragma unroll
        for (int j = 0; j < 8; ++j) w[j] = (__bf16)(f[r * 8 + j] * inv);
        *(bf16x8*)&p[(r * 64 + lane) * 8] = w;
    }
}

template<class CF>
__global__ __launch_bounds__(64, 2)
void gemm1w(const __bf16* __restrict__ A, const __bf16* __restrict__ B,
            const float* __restrict__ bias,
            typename CF::OUT_T* __restrict__ C, typename CF::OUT_T* __restrict__ CT,
            int M, int N, int K, int ntx)
{
    __shared__ __bf16 sAB[8192];   // sA[2][2048] + sB[2][2048] = 16 KB
    gemm_body<CF>(blockIdx.x, sAB, sAB + 4096, A, B, bias, C, CT, M, N, K, ntx);
}

// Two GEMMs fused.
template<class C1, class C2>
__global__ __launch_bounds__(64, 2)
void gemm2w(int nblk1,
            const __bf16* __restrict__ A1, const __bf16* __restrict__ B1,
            const float* __restrict__ b1,
            typename C1::OUT_T* __restrict__ C1p, typename C1::OUT_T* __restrict__ CT1,
            int M1, int N1, int K1, int ntx1,
            const __bf16* __restrict__ A2, const __bf16* __restrict__ B2,
            const float* __restrict__ b2,
            typename C2::OUT_T* __restrict__ C2p, typename C2::OUT_T* __restrict__ CT2,
            int M2, int N2, int K2, int ntx2)
{
    __shared__ __bf16 sAB[8192];
    const int b = blockIdx.x;
    if (b < nblk1)
        gemm_body<C1>(b, sAB, sAB + 4096, A1, B1, b1, C1p, CT1, M1, N1, K1, ntx1);
    else
        gemm_body<C2>(b - nblk1, sAB, sAB + 4096, A2, B2, b2, C2p, CT2, M2, N2, K2, ntx2);
}

// Two GEMMs + row-softmax batch fused.
template<class C1, class C2>
__global__ __launch_bounds__(64, 2)
void gemm2smw(int nblk1, int nblk2,
              const __bf16* __restrict__ A1, const __bf16* __restrict__ B1,
              const float* __restrict__ b1, typename C1::OUT_T* __restrict__ C1p,
              int M1, int N1, int K1, int ntx1,
              const __bf16* __restrict__ A2, const __bf16* __restrict__ B2,
              const float* __restrict__ b2, typename C2::OUT_T* __restrict__ C2p,
              int M2, int N2, int K2, int ntx2,
              __bf16* __restrict__ SM)
{
    __shared__ __bf16 sAB[8192];
    const int b = blockIdx.x;
    if (b < nblk1)
        gemm_body<C1>(b, sAB, sAB + 4096, A1, B1, b1, C1p,
                      (typename C1::OUT_T*)nullptr, M1, N1, K1, ntx1);
    else if (b < nblk1 + nblk2)
        gemm_body<C2>(b - nblk1, sAB, sAB + 4096, A2, B2, b2, C2p,
                      (typename C2::OUT_T*)nullptr, M2, N2, K2, ntx2);
    else
        softmax_row_w(SM + (size_t)(b - nblk1 - nblk2) * 2048);
}

__global__ __launch_bounds__(64)
void row_softmax_w(__bf16* __restrict__ A)
{
    softmax_row_w(A + (size_t)blockIdx.x * 2048);
}

// ---------------- prep (unchanged, 256-thread) ----------------
__device__ __forceinline__ void tp_tile(const float* __restrict__ in,
                                        __bf16* __restrict__ outp,
                                        int R, int C, int bx, int by)
{
    __shared__ float t[32][33];
    const int tx = threadIdx.x & 31, ty = threadIdx.x >> 5;
    #pragma unroll
    for (int i = ty; i < 32; i += 8)
        t[i][tx] = in[(size_t)(by + i) * C + (bx + tx)];
    __syncthreads();
    #pragma unroll
    for (int i = ty; i < 32; i += 8)
        outp[(size_t)(bx + i) * R + (by + tx)] = (__bf16)t[tx][i];
}

__device__ __forceinline__ void cast_blk(const float* __restrict__ s,
                                         __bf16* __restrict__ d, int blk)
{
    const int i = blk * 1024 + threadIdx.x * 4;
    float4 v = *(const float4*)&s[i];
    bf16x4 w = { (__bf16)v.x, (__bf16)v.y, (__bf16)v.z, (__bf16)v.w };
    *(bf16x4*)&d[i] = w;
}

__global__ __launch_bounds__(256)
void prep(const float* __restrict__ vc, __bf16* __restrict__ vcT,
          const float* __restrict__ vm, __bf16* __restrict__ vmT,
          const float* __restrict__ W_ak, __bf16* __restrict__ W_akb,
          const float* __restrict__ W_c, __bf16* __restrict__ W_cb,
          const float* __restrict__ W_mad, __bf16* __restrict__ W_madb,
          const float* __restrict__ W_gcn, __bf16* __restrict__ W_gcnT)
{
    const int x = blockIdx.x;
    if (blockIdx.z == 0) {
        const float* in = (x < 2048) ? vc : vm;
        __bf16* o       = (x < 2048) ? vcT : vmT;
        const int e = x & 2047;
        tp_tile(in, o, 1024, 2048, (e & 63) * 32, (e >> 6) * 32);
    } else if (blockIdx.z == 1) {
        if (x < 2048)      cast_blk(W_ak, W_akb, x);
        else if (x < 3072) cast_blk(W_c, W_cb, x - 2048);
        else               cast_blk(W_mad, W_madb, x - 3072);
    } else {
        if (x >= 1024) return;
        tp_tile(W_gcn, W_gcnT, 1024, 1024, (x & 31) * 32, (x >> 5) * 32);
    }
}

extern "C" void kernel_launch(void* const* d_in, const int* in_sizes, int n_in,
                              void* d_out, int out_size, void* d_ws, size_t ws_size,
                              hipStream_t stream)
{
    const float* vc    = (const float*)d_in[0];
    const float* vm    = (const float*)d_in[1];
    const float* W_ak  = (const float*)d_in[2];
    const float* b_ak  = (const float*)d_in[3];
    const float* W_c   = (const float*)d_in[4];
    const float* b_c   = (const float*)d_in[5];
    const float* W_mad = (const float*)d_in[6];
    const float* b_mad = (const float*)d_in[7];
    const float* W_gcn = (const float*)d_in[8];
    const float* b_gcn = (const float*)d_in[9];
    float* out = (float*)d_out;

    // Arena, 32 MB (same as r11):
    //  [0,8):   ST (wL2, smL3, rL4)  -> P (wL5, smL6, rL7)
    //  [8,12):  vcT (wL1, rL2)       -> vmaT (wL4, rL5)
    //  [12,16): W_akb (wL1, rL2)     -> vmm (wL3, rL4)
    //  [16,20): vmT (wL1, rL2)       -> xT (wL3, rL7)
    //  [20,22): W_cb (wL1, rL2)
    //  [22,24): W_madb (wL1, rL3)
    //  [24,28): vmrT (wL2, rL3)
    //  [28,30): W_gcnT (wL1, rL3)
    char* ws = (char*)d_ws;
    const size_t MB = 1u << 20;
    __bf16* ST     = (__bf16*)(ws);
    __bf16* P      = (__bf16*)(ws);
    __bf16* vcT    = (__bf16*)(ws + 8 * MB);
    __bf16* vmaT   = (__bf16*)(ws + 8 * MB);
    __bf16* W_akb  = (__bf16*)(ws + 12 * MB);
    __bf16* vmm    = (__bf16*)(ws + 12 * MB);
    __bf16* vmT    = (__bf16*)(ws + 16 * MB);
    __bf16* xT     = (__bf16*)(ws + 16 * MB);
    __bf16* W_cb   = (__bf16*)(ws + 20 * MB);
    __bf16* W_madb = (__bf16*)(ws + 22 * MB);
    __bf16* vmrT   = (__bf16*)(ws + 24 * MB);
    __bf16* W_gcnT = (__bf16*)(ws + 28 * MB);

    using G3  = GC<__bf16, 2, false, 0>;   // ST = vcT*W_akb + b_ak[col]
    using G5  = GC<__bf16, 1, true,  1>;   // vmrT = relu(W_cb*vmT + b_c[row])^T
    using G6  = GC<__bf16, 0, false, 0>;   // vmm = W_madb*vmrT
    using G11 = GC<__bf16, 1, false, 0>;   // xT = W_gcnT*vmrT + b_gcn[row]
    using G7  = GC<__bf16, 2, false, 0>;   // vmaT = ST_sm*vmm + b_mad[col]
    using G9  = GC<__bf16, 0, false, 0>;   // P = vmaT*vmaT^T
    using G12 = GC<float,  0, false, 1>;   // out = (P_sm*xT)^T fp32

    // L1. input casts/transposes
    prep<<<dim3(4096, 1, 3), 256, 0, stream>>>(vc, vcT, vm, vmT, W_ak, W_akb,
                                               W_c, W_cb, W_mad, W_madb,
                                               W_gcn, W_gcnT);
    // L2. [G3 1024 | G5 512] = 1536 single-wave blocks
    gemm2w<G3, G5><<<1536, 64, 0, stream>>>(1024,
        vcT, W_akb, b_ak, ST, (__bf16*)nullptr, 2048, 2048, 1024, 32,
        W_cb, vmT, b_c, (__bf16*)nullptr, vmrT, 1024, 2048, 1024, 32);
    // L3. [G6 512 | G11 512 | smST 2048] = 3072 blocks
    gemm2smw<G6, G11><<<3072, 64, 0, stream>>>(512, 512,
        W_madb, vmrT, nullptr, vmm, 1024, 2048, 1024, 32,
        W_gcnT, vmrT, b_gcn, xT, 1024, 2048, 1024, 32,
        ST);
    // L4. G7: vmaT = ST_sm*vmm + b_mad (2048x1024 K2048), 512 blocks
    gemm1w<G7><<<512, 64, 0, stream>>>(ST, vmm, b_mad, vmaT, (__bf16*)nullptr,
                                       2048, 1024, 2048, 16);
    // L5. G9: P = vmaT*vmaT^T (2048x2048 K1024), 1024 blocks
    gemm1w<G9><<<1024, 64, 0, stream>>>(vmaT, vmaT, nullptr, P, (__bf16*)nullptr,
                                        2048, 2048, 1024, 32);
    // L6. softmax rows of P
    row_softmax_w<<<2048, 64, 0, stream>>>(P);
    // L7. G12: out = (P*xT)^T direct fp32 (2048x1024 K2048), 512 blocks
    gemm1w<G12><<<512, 64, 0, stream>>>(P, xT, nullptr, (float*)nullptr, out,
                                        2048, 1024, 2048, 16);
}